// Round 6
// baseline (306.026 us; speedup 1.0000x reference)
//
#include <hip/hip_runtime.h>

#define KDIM 128
#define NTOT (KDIM * KDIM * KDIM)
#define BPD 8           // bins per dim
#define NBINS (BPD * BPD * BPD)
#define BINW 16         // cells per bin per dim
#define TILE_D 19       // 16 + 3 halo
#define T2 (TILE_D * TILE_D)
#define TILE_N (TILE_D * TILE_D * TILE_D)
#define TSTRIDE 6912    // padded tile stride (floats)
#define CHUNK 512
#define NSCALE_BLK 1024
#define ST 17           // LDS row stride (float2) for transpose stages

static constexpr float PI_F = 3.14159265358979323846f;
static constexpr float TWO_PI_F = 6.28318530717958647692f;
static constexpr float KE_F = 14.3996f;
static constexpr float ALPHA_F = 0.35f;

__device__ __forceinline__ int brev7(int i) { return (int)(__brev((unsigned)i) >> 25); }

__device__ __forceinline__ void inv3x3(const float* c, float* inv, float* adet) {
    float a00 = c[0], a01 = c[1], a02 = c[2];
    float a10 = c[3], a11 = c[4], a12 = c[5];
    float a20 = c[6], a21 = c[7], a22 = c[8];
    float det = a00 * (a11 * a22 - a12 * a21) - a01 * (a10 * a22 - a12 * a20) +
                a02 * (a10 * a21 - a11 * a20);
    float id = 1.0f / det;
    inv[0] = (a11 * a22 - a12 * a21) * id;
    inv[1] = (a02 * a21 - a01 * a22) * id;
    inv[2] = (a01 * a12 - a02 * a11) * id;
    inv[3] = (a12 * a20 - a10 * a22) * id;
    inv[4] = (a00 * a22 - a02 * a20) * id;
    inv[5] = (a02 * a10 - a00 * a12) * id;
    inv[6] = (a10 * a21 - a11 * a20) * id;
    inv[7] = (a01 * a20 - a00 * a21) * id;
    inv[8] = (a00 * a11 - a01 * a10) * id;
    *adet = fabsf(det);
}

__device__ __forceinline__ void bspline4(float f, float* w, float* dw) {
    float f2 = f * f, f3 = f2 * f;
    float omf = 1.0f - f;
    w[0] = omf * omf * omf * (1.0f / 6.0f);
    w[1] = (3.0f * f3 - 6.0f * f2 + 4.0f) * (1.0f / 6.0f);
    w[2] = (-3.0f * f3 + 3.0f * f2 + 3.0f * f + 1.0f) * (1.0f / 6.0f);
    w[3] = f3 * (1.0f / 6.0f);
    dw[0] = -0.5f * omf * omf;
    dw[1] = 1.5f * f2 - 2.0f * f;
    dw[2] = -1.5f * f2 + f + 0.5f;
    dw[3] = 0.5f * f2;
}

__device__ __forceinline__ void atom_base(const float* __restrict__ pos, const float* inv,
                                          int i, int base[3], float fpart[3]) {
    float p0 = pos[3 * i], p1 = pos[3 * i + 1], p2 = pos[3 * i + 2];
#pragma unroll
    for (int d = 0; d < 3; d++) {
        float fr = p0 * inv[d] + p1 * inv[3 + d] + p2 * inv[6 + d];
        fr -= floorf(fr);
        float u = fr * (float)KDIM;
        float bs = floorf(u);
        fpart[d] = u - bs;
        int b = (int)bs;
        base[d] = b & (KDIM - 1);
    }
}

// ---------------- binning: histogram + per-block sum(q^2) ----------------
__global__ __launch_bounds__(256) void hist_kernel(const float* __restrict__ pos,
                                                   const float* __restrict__ chg,
                                                   const float* __restrict__ cell,
                                                   int* __restrict__ counts,
                                                   float* __restrict__ q2_part, int n) {
    __shared__ float hred[4];
    int i = blockIdx.x * blockDim.x + threadIdx.x;
    float q2 = 0.0f;
    if (i < n) {
        float inv[9], det;
        inv3x3(cell, inv, &det);
        int base[3];
        float fp[3];
        atom_base(pos, inv, i, base, fp);
        int bid = ((base[0] >> 4) << 6) | ((base[1] >> 4) << 3) | (base[2] >> 4);
        atomicAdd(&counts[bid], 1);
        float qi = chg[i];
        q2 = qi * qi;
    }
#pragma unroll
    for (int off = 32; off; off >>= 1) q2 += __shfl_down(q2, off);
    if ((threadIdx.x & 63) == 0) hred[threadIdx.x >> 6] = q2;
    __syncthreads();
    if (threadIdx.x == 0) q2_part[blockIdx.x] = hred[0] + hred[1] + hred[2] + hred[3];
}

__global__ __launch_bounds__(256) void scan_kernel(const int* __restrict__ counts,
                                                   int* __restrict__ starts) {
    __shared__ int part[256];
    int tid = threadIdx.x;
    int local[NBINS / 256];
    int sum = 0;
#pragma unroll
    for (int k = 0; k < NBINS / 256; k++) {
        local[k] = counts[tid * (NBINS / 256) + k];
        sum += local[k];
    }
    part[tid] = sum;
    __syncthreads();
    if (tid == 0) {
        int acc = 0;
        for (int i = 0; i < 256; i++) {
            int t = part[i];
            part[i] = acc;
            acc += t;
        }
        starts[NBINS] = acc;
    }
    __syncthreads();
    int acc = part[tid];
#pragma unroll
    for (int k = 0; k < NBINS / 256; k++) {
        starts[tid * (NBINS / 256) + k] = acc;
        acc += local[k];
    }
}

// scatter: weights record (64B) in bin-sorted order + atom id list
// record: [0..3]=q*wx, [4..7]=wy, [8..11]=wz, [12]=loc bits, [13..15]=pad
__global__ __launch_bounds__(256) void scatter_kernel(const float* __restrict__ pos,
                                                      const float* __restrict__ chg,
                                                      const float* __restrict__ cell,
                                                      const int* __restrict__ starts,
                                                      int* __restrict__ cursor,
                                                      float* __restrict__ records,
                                                      int* __restrict__ binatoms, int n) {
    int i = blockIdx.x * blockDim.x + threadIdx.x;
    if (i >= n) return;
    float inv[9], det;
    inv3x3(cell, inv, &det);
    int base[3];
    float fp[3];
    atom_base(pos, inv, i, base, fp);
    int bid = ((base[0] >> 4) << 6) | ((base[1] >> 4) << 3) | (base[2] >> 4);
    int slot = atomicAdd(&cursor[bid], 1) + starts[bid];
    binatoms[slot] = i;
    float4* rec = (float4*)(records + (size_t)slot * 16);
    float w[4], dw[4];
    float qi = chg[i];
    bspline4(fp[0], w, dw);
    rec[0] = make_float4(qi * w[0], qi * w[1], qi * w[2], qi * w[3]);
    bspline4(fp[1], w, dw);
    rec[1] = make_float4(w[0], w[1], w[2], w[3]);
    bspline4(fp[2], w, dw);
    rec[2] = make_float4(w[0], w[1], w[2], w[3]);
    int loc = (base[0] & 15) | ((base[1] & 15) << 4) | ((base[2] & 15) << 8);
    rec[3] = make_float4(__int_as_float(loc), 0.0f, 0.0f, 0.0f);
}

// -------- spreading: one wave per atom, lane = (j0,j1,j2) -> distinct LDS cells ------
__global__ __launch_bounds__(512) void spread_bins_kernel(
    const float* __restrict__ records, const int* __restrict__ starts,
    float* __restrict__ tiles) {
    __shared__ float tile[TILE_N];
    __shared__ float4 arec[CHUNK * 4];
    int tid = threadIdx.x;
    int bid = blockIdx.x;
    for (int i = tid; i < TILE_N; i += 512) tile[i] = 0.0f;
    int s = starts[bid], e = starts[bid + 1];
    int w = tid >> 6, l = tid & 63;
    int j0 = l >> 4, j1 = (l >> 2) & 3, j2 = l & 3;
    int joff = j0 * T2 + j1 * TILE_D + j2;
    for (int c0 = s; c0 < e; c0 += CHUNK) {
        int cnt = min(CHUNK, e - c0);
        __syncthreads();
        if (tid < cnt) {
            const float4* rp = (const float4*)records + (size_t)(c0 + tid) * 4;
            arec[tid * 4 + 0] = rp[0];
            arec[tid * 4 + 1] = rp[1];
            arec[tid * 4 + 2] = rp[2];
            arec[tid * 4 + 3] = rp[3];
        }
        __syncthreads();
        for (int a = w; a < cnt; a += 8) {
            const float* A = (const float*)&arec[a << 2];
            float val = A[j0] * A[4 + j1] * A[8 + j2];
            int lc = __float_as_int(A[12]);
            int tb = (lc & 15) * T2 + ((lc >> 4) & 15) * TILE_D + ((lc >> 8) & 15);
            atomicAdd(&tile[tb + joff], val);
        }
    }
    __syncthreads();
    float* tout = tiles + (size_t)bid * TSTRIDE;
    for (int i = tid; i < TILE_N; i += 512) tout[i] = tile[i];
}

// ---------------- wave FFTs: DIF (natural->scrambled), DIT (scrambled->natural) ------
__device__ __forceinline__ float2 cmul(float2 a, float cs, float sn) {
    return make_float2(a.x * cs - a.y * sn, a.x * sn + a.y * cs);
}

__device__ __forceinline__ void wave_fft128_dif(float2& v0, float2& v1, int l, float sign) {
    {
        float ang = sign * (PI_F / 64.0f) * (float)l;
        float sn, cs;
        __sincosf(ang, &sn, &cs);
        float2 d = make_float2(v0.x - v1.x, v0.y - v1.y);
        v0 = make_float2(v0.x + v1.x, v0.y + v1.y);
        v1 = cmul(d, cs, sn);
    }
#pragma unroll
    for (int m = 32; m >= 1; m >>= 1) {
        float ang = sign * (PI_F / (float)m) * (float)(l & (m - 1));
        float sn, cs;
        __sincosf(ang, &sn, &cs);
        bool hi = (l & m) != 0;
        float2 p0, p1;
        p0.x = __shfl_xor(v0.x, m);
        p0.y = __shfl_xor(v0.y, m);
        p1.x = __shfl_xor(v1.x, m);
        p1.y = __shfl_xor(v1.y, m);
        float2 a0 = hi ? cmul(make_float2(p0.x - v0.x, p0.y - v0.y), cs, sn)
                       : make_float2(v0.x + p0.x, v0.y + p0.y);
        float2 a1 = hi ? cmul(make_float2(p1.x - v1.x, p1.y - v1.y), cs, sn)
                       : make_float2(v1.x + p1.x, v1.y + p1.y);
        v0 = a0;
        v1 = a1;
    }
}

__device__ __forceinline__ void wave_fft128_dit(float2& v0, float2& v1, int l, float sign) {
#pragma unroll
    for (int m = 1; m <= 32; m <<= 1) {
        float2 p0, p1;
        p0.x = __shfl_xor(v0.x, m);
        p0.y = __shfl_xor(v0.y, m);
        p1.x = __shfl_xor(v1.x, m);
        p1.y = __shfl_xor(v1.y, m);
        float ang = sign * (PI_F / (float)m) * (float)(l & (m - 1));
        float sn, cs;
        __sincosf(ang, &sn, &cs);
        bool hi = (l & m) != 0;
        float2 o0 = hi ? v0 : p0, e0 = hi ? p0 : v0;
        float2 o1 = hi ? v1 : p1, e1 = hi ? p1 : v1;
        float2 t0 = cmul(o0, cs, sn);
        float2 t1 = cmul(o1, cs, sn);
        float s = hi ? -1.0f : 1.0f;
        v0 = make_float2(e0.x + s * t0.x, e0.y + s * t0.y);
        v1 = make_float2(e1.x + s * t1.x, e1.y + s * t1.y);
    }
    float ang = sign * (PI_F / 64.0f) * (float)l;
    float sn, cs;
    __sincosf(ang, &sn, &cs);
    float2 t = cmul(v1, cs, sn);
    float2 e = v0;
    v0 = make_float2(e.x + t.x, e.y + t.y);
    v1 = make_float2(e.x - t.x, e.y - t.y);
}

// ---- forward z FFT with tile merge fused in ----
__global__ __launch_bounds__(512) void fft_z_merge(const float* __restrict__ tiles,
                                                   float2* __restrict__ C) {
    int w = threadIdx.x >> 6, l = threadIdx.x & 63;
    int line = (blockIdx.x << 3) + w;
    int gx = line >> 7, gy = line & 127;
    int bx = gx >> 4, ox = gx & 15;
    int by = gy >> 4, oy = gy & 15;
    int nx = (ox >= 13) ? 2 : 1, ny = (oy >= 13) ? 2 : 1;
    int bxs[2] = {bx, (bx + 1) & 7}, lxs[2] = {ox + 3, ox - 13};
    int bys[2] = {by, (by + 1) & 7}, lys[2] = {oy + 3, oy - 13};
    float2 v0, v1;
#pragma unroll
    for (int h = 0; h < 2; h++) {
        int gz = l + (h << 6);
        int bz = gz >> 4, oz = gz & 15;
        int nz = (oz >= 13) ? 2 : 1;
        int bzs[2] = {bz, (bz + 1) & 7}, lzs[2] = {oz + 3, oz - 13};
        float v = 0.0f;
        for (int i = 0; i < nx; i++)
            for (int j = 0; j < ny; j++) {
                int bxy = (bxs[i] << 6) | (bys[j] << 3);
                int lo = lxs[i] * T2 + lys[j] * TILE_D;
                for (int k = 0; k < nz; k++)
                    v += tiles[(size_t)(bxy | bzs[k]) * TSTRIDE + lo + lzs[k]];
            }
        if (h == 0) v0 = make_float2(v, 0.0f);
        else v1 = make_float2(v, 0.0f);
    }
    wave_fft128_dif(v0, v1, l, -1.0f);
    int base = line << 7;
    C[base + l] = v0;
    C[base + l + 64] = v1;
}

// ---- inverse z FFT (DIT), writes real potential mesh as float ----
__global__ __launch_bounds__(512) void fft_z_phi(const float2* __restrict__ C,
                                                 float* __restrict__ phi) {
    int w = threadIdx.x >> 6, l = threadIdx.x & 63;
    int line = (blockIdx.x << 3) + w;
    int base = line << 7;
    float2 v0 = C[base + l];
    float2 v1 = C[base + l + 64];
    wave_fft128_dit(v0, v1, l, 1.0f);
    phi[base + l] = v0.x;
    phi[base + l + 64] = v1.x;
}

// ---- FFT along strided dim (y). DIF=1 fwd, DIF=0 inv. 16-z chunks, LDS transpose. ---
template <int DIF>
__global__ __launch_bounds__(512) void fft_t(float2* __restrict__ C, int LS, int OS,
                                             float sign) {
    __shared__ float2 lds[128 * ST];
    int tid = threadIdx.x;
    int p = blockIdx.x >> 3;
    int z0 = (blockIdx.x & 7) << 4;
    int base = p * OS + z0;
#pragma unroll
    for (int k = 0; k < 2; k++) {
        int e = tid + (k << 9);
        int ll = e >> 3, zq = e & 7;
        float4 f = ((const float4*)C)[(base >> 1) + ll * (LS >> 1) + zq];
        lds[ll * ST + 2 * zq] = make_float2(f.x, f.y);
        lds[ll * ST + 2 * zq + 1] = make_float2(f.z, f.w);
    }
    __syncthreads();
    int w = tid >> 6, l = tid & 63;
#pragma unroll
    for (int c = 0; c < 2; c++) {
        int zt = (w << 1) | c;
        float2 v0 = lds[l * ST + zt];
        float2 v1 = lds[(l + 64) * ST + zt];
        if (DIF) wave_fft128_dif(v0, v1, l, sign);
        else wave_fft128_dit(v0, v1, l, sign);
        lds[l * ST + zt] = v0;
        lds[(l + 64) * ST + zt] = v1;
    }
    __syncthreads();
#pragma unroll
    for (int k = 0; k < 2; k++) {
        int e = tid + (k << 9);
        int ll = e >> 3, zq = e & 7;
        float2 a = lds[ll * ST + 2 * zq];
        float2 b = lds[ll * ST + 2 * zq + 1];
        ((float4*)C)[(base >> 1) + ll * (LS >> 1) + zq] = make_float4(a.x, a.y, b.x, b.y);
    }
}

// ---------------- scrambled-order m and |b|^-2 tables ----------------
__device__ __forceinline__ float bmod2f(int x) {
    float th = (TWO_PI_F / (float)KDIM) * (float)x;
    float s1, c1, s2, c2;
    __sincosf(th, &s1, &c1);
    __sincosf(th + th, &s2, &c2);
    float dr = 0.16666667f + 0.66666667f * c1 + 0.16666667f * c2;
    float di = 0.66666667f * s1 + 0.16666667f * s2;
    float d2 = dr * dr + di * di;
    return 1.0f / fmaxf(d2, 1e-12f);
}

__global__ void tbl_kernel(float* __restrict__ mtblS, float* __restrict__ btblS) {
    int i = threadIdx.x;
    if (i < KDIM) {
        int r = brev7(i);
        mtblS[i] = (float)(r < 64 ? r : r - 128);
        btblS[i] = bmod2f(r);
    }
}

// --------- fused: fwd x-DIF + scale (scrambled order) + energy + inv x-DIT ---------
__global__ __launch_bounds__(512) void fft_x_scale(float2* __restrict__ C,
                                                   const float* __restrict__ cell,
                                                   const float* __restrict__ mtblS,
                                                   const float* __restrict__ btblS,
                                                   float* __restrict__ scale_part) {
    __shared__ float2 lds[128 * ST];
    __shared__ float red[8];
    const int LS = KDIM * KDIM, OS = KDIM;
    int tid = threadIdx.x;
    int p = blockIdx.x >> 3;            // y slot
    int z0 = (blockIdx.x & 7) << 4;     // z chunk
    int base = p * OS + z0;
#pragma unroll
    for (int k = 0; k < 2; k++) {
        int e = tid + (k << 9);
        int ll = e >> 3, zq = e & 7;
        float4 f = ((const float4*)C)[(base >> 1) + ll * (LS >> 1) + zq];
        lds[ll * ST + 2 * zq] = make_float2(f.x, f.y);
        lds[ll * ST + 2 * zq + 1] = make_float2(f.z, f.w);
    }
    __syncthreads();
    int w = tid >> 6, l = tid & 63;
    float inv[9], det;
    inv3x3(cell, inv, &det);
    float my = mtblS[p];
    float by = btblS[p];
    float contrib = 0.0f;
#pragma unroll
    for (int c = 0; c < 2; c++) {
        int zt = (w << 1) | c;
        float2 v0 = lds[l * ST + zt];
        float2 v1 = lds[(l + 64) * ST + zt];
        wave_fft128_dif(v0, v1, l, -1.0f);
        int z = z0 + zt;
        float mz = mtblS[z];
        float byz = by * btblS[z];
#pragma unroll
        for (int h = 0; h < 2; h++) {
            int xs = l + (h << 6);      // x slot
            float mx = mtblS[xs];
            float kx = TWO_PI_F * (mx * inv[0] + my * inv[1] + mz * inv[2]);
            float ky = TWO_PI_F * (mx * inv[3] + my * inv[4] + mz * inv[5]);
            float kz = TWO_PI_F * (mx * inv[6] + my * inv[7] + mz * inv[8]);
            float k2 = kx * kx + ky * ky + kz * kz;
            float A = 0.0f;
            if (k2 > 0.0f)
                A = __expf(-k2 / (4.0f * ALPHA_F * ALPHA_F)) / k2 * btblS[xs] * byz;
            float2& v = h ? v1 : v0;
            contrib += A * (v.x * v.x + v.y * v.y);
            v.x *= A;
            v.y *= A;
        }
        wave_fft128_dit(v0, v1, l, 1.0f);
        lds[l * ST + zt] = v0;
        lds[(l + 64) * ST + zt] = v1;
    }
#pragma unroll
    for (int off = 32; off; off >>= 1) contrib += __shfl_down(contrib, off);
    if (l == 0) red[w] = contrib;
    __syncthreads();
    if (tid == 0) {
        float v = 0.0f;
        for (int i = 0; i < 8; i++) v += red[i];
        scale_part[blockIdx.x] = v;
    }
#pragma unroll
    for (int k = 0; k < 2; k++) {
        int e = tid + (k << 9);
        int ll = e >> 3, zq = e & 7;
        float2 a = lds[ll * ST + 2 * zq];
        float2 b = lds[ll * ST + 2 * zq + 1];
        ((float4*)C)[(base >> 1) + ll * (LS >> 1) + zq] = make_float4(a.x, a.y, b.x, b.y);
    }
}

// ---------------- energy finalize ----------------
__global__ __launch_bounds__(256) void finalize_kernel(const float* __restrict__ scale_part,
                                                       const float* __restrict__ q2_part,
                                                       int nq2,
                                                       const float* __restrict__ cell,
                                                       float* __restrict__ out) {
    __shared__ double sd[256];
    int tid = threadIdx.x;
    double es = 0.0;
    for (int i = tid; i < NSCALE_BLK; i += 256) es += (double)scale_part[i];
    double q2 = 0.0;
    for (int i = tid; i < nq2; i += 256) q2 += (double)q2_part[i];
    sd[tid] = es;
    __syncthreads();
    for (int s = 128; s; s >>= 1) {
        if (tid < s) sd[tid] += sd[tid + s];
        __syncthreads();
    }
    double esum = sd[0];
    __syncthreads();
    sd[tid] = q2;
    __syncthreads();
    for (int s = 128; s; s >>= 1) {
        if (tid < s) sd[tid] += sd[tid + s];
        __syncthreads();
    }
    if (tid == 0) {
        float inv[9], det;
        inv3x3(cell, inv, &det);
        double c = (double)KE_F * 2.0 * 3.14159265358979323846 / (double)det;
        double e = c * esum -
                   (double)KE_F * (double)ALPHA_F / 1.7724538509055160273 * sd[0];
        out[0] = (float)e;
    }
}

// ---------------- force gather via LDS-staged phi tiles ----------------
__global__ __launch_bounds__(512) void gather_bins_kernel(
    const float* __restrict__ pos, const float* __restrict__ chg,
    const float* __restrict__ cell, const int* __restrict__ starts,
    const int* __restrict__ binatoms, const float* __restrict__ phi,
    float* __restrict__ out) {
    __shared__ float tile[TILE_N];
    int tid = threadIdx.x;
    int bid = blockIdx.x;
    int s = starts[bid], e = starts[bid + 1];
    if (s == e) return;
    int bx = bid >> 6, by = (bid >> 3) & 7, bz = bid & 7;
    int gx0 = (bx << 4) - 3, gy0 = (by << 4) - 3, gz0 = (bz << 4) - 3;
    for (int i = tid; i < TILE_N; i += 512) {
        int lx = i / T2;
        int r = i - lx * T2;
        int ly = r / TILE_D;
        int lz = r - ly * TILE_D;
        int gx = (gx0 + lx) & 127, gy = (gy0 + ly) & 127, gz = (gz0 + lz) & 127;
        tile[i] = phi[(gx << 14) + (gy << 7) + gz];
    }
    __syncthreads();
    float inv[9], det;
    inv3x3(cell, inv, &det);
    for (int a = s + tid; a < e; a += 512) {
        int i = binatoms[a];
        int base[3];
        float fp[3];
        atom_base(pos, inv, i, base, fp);
        float wx[4], wy[4], wz[4], dx[4], dy[4], dz[4];
        bspline4(fp[0], wx, dx);
        bspline4(fp[1], wy, dy);
        bspline4(fp[2], wz, dz);
        int tb0 = (base[0] & 15) * T2 + (base[1] & 15) * TILE_D + (base[2] & 15);
        float acc0 = 0.0f, acc1 = 0.0f, acc2 = 0.0f;
#pragma unroll
        for (int j0 = 0; j0 < 4; j0++) {
#pragma unroll
            for (int j1 = 0; j1 < 4; j1++) {
                float cA = dx[j0] * wy[j1];
                float cB = wx[j0] * dy[j1];
                float cC = wx[j0] * wy[j1];
                int tb = tb0 + j0 * T2 + j1 * TILE_D;
#pragma unroll
                for (int j2 = 0; j2 < 4; j2++) {
                    float p = tile[tb + j2];
                    acc0 += p * cA * wz[j2];
                    acc1 += p * cB * wz[j2];
                    acc2 += p * cC * dz[j2];
                }
            }
        }
        float qi = chg[i];
        float c = KE_F * TWO_PI_F / det;
        float fac = -2.0f * c * qi * (float)KDIM;
        out[1 + 3 * i + 0] = fac * (acc0 * inv[0] + acc1 * inv[1] + acc2 * inv[2]);
        out[1 + 3 * i + 1] = fac * (acc0 * inv[3] + acc1 * inv[4] + acc2 * inv[5]);
        out[1 + 3 * i + 2] = fac * (acc0 * inv[6] + acc1 * inv[7] + acc2 * inv[8]);
    }
}

extern "C" void kernel_launch(void* const* d_in, const int* in_sizes, int n_in,
                              void* d_out, int out_size, void* d_ws, size_t ws_size,
                              hipStream_t stream) {
    const float* pos = (const float*)d_in[0];
    const float* chg = (const float*)d_in[1];
    const float* cell = (const float*)d_in[2];
    float* out = (float*)d_out;
    int n = in_sizes[1];
    int nb = (n + 255) / 256;

    char* w = (char*)d_ws;
    float2* C = (float2*)w;                       // 16.78 MB; records alias this
    size_t off = (size_t)NTOT * sizeof(float2);
    float* tiles = (float*)(w + off);             // 14.16 MB; phi aliases this
    off += (size_t)NBINS * TSTRIDE * sizeof(float);
    int* counts = (int*)(w + off);                // NBINS (zeroed)
    size_t zoff = off;
    off += NBINS * sizeof(int);
    int* cursor = (int*)(w + off);                // NBINS (zeroed)
    off += NBINS * sizeof(int);
    size_t zero_bytes = off - zoff;
    int* starts = (int*)(w + off);                // NBINS+1
    off += (NBINS + 1) * sizeof(int);
    int* binatoms = (int*)(w + off);              // n
    off += (size_t)n * sizeof(int);
    float* scale_part = (float*)(w + off);        // NSCALE_BLK
    off += NSCALE_BLK * sizeof(float);
    float* q2_part = (float*)(w + off);           // nb
    off += (size_t)nb * sizeof(float);
    float* mtblS = (float*)(w + off);             // 128
    off += KDIM * sizeof(float);
    float* btblS = (float*)(w + off);             // 128

    float* records = (float*)C;                   // dead after spread_bins
    float* phi = (float*)tiles;                   // tiles dead after fft_z_merge

    hipMemsetAsync(w + zoff, 0, zero_bytes, stream);

    tbl_kernel<<<1, 128, 0, stream>>>(mtblS, btblS);
    hist_kernel<<<nb, 256, 0, stream>>>(pos, chg, cell, counts, q2_part, n);
    scan_kernel<<<1, 256, 0, stream>>>(counts, starts);
    scatter_kernel<<<nb, 256, 0, stream>>>(pos, chg, cell, starts, cursor, records,
                                           binatoms, n);
    spread_bins_kernel<<<NBINS, 512, 0, stream>>>(records, starts, tiles);

    fft_z_merge<<<2048, 512, 0, stream>>>(tiles, C);                    // fwd z (DIF)
    fft_t<1><<<1024, 512, 0, stream>>>(C, KDIM, KDIM * KDIM, -1.0f);    // fwd y (DIF)
    fft_x_scale<<<NSCALE_BLK, 512, 0, stream>>>(C, cell, mtblS, btblS, scale_part);
    fft_t<0><<<1024, 512, 0, stream>>>(C, KDIM, KDIM * KDIM, 1.0f);     // inv y (DIT)
    fft_z_phi<<<2048, 512, 0, stream>>>(C, phi);                        // inv z (DIT)

    finalize_kernel<<<1, 256, 0, stream>>>(scale_part, q2_part, nb, cell, out);
    gather_bins_kernel<<<NBINS, 512, 0, stream>>>(pos, chg, cell, starts, binatoms, phi,
                                                  out);
}

// Round 7
// 177.903 us; speedup vs baseline: 1.7202x; 1.7202x over previous
//
#include <hip/hip_runtime.h>

#define KDIM 128
#define NTOT (KDIM * KDIM * KDIM)
#define BPD 16          // bins per dim
#define NBINS (BPD * BPD * BPD)
#define TILE_D 11       // 8 + 3 halo
#define T2 (TILE_D * TILE_D)
#define TILE_N (TILE_D * TILE_D * TILE_D)
#define TPAD 1332       // per-wave LDS tile stride (floats)
#define TSTRIDE 1344    // padded global tile stride (floats)
#define CHUNK 256
#define NSCALE_BLK 1024
#define ST 17           // LDS row stride (float2) for transpose stages

static constexpr float PI_F = 3.14159265358979323846f;
static constexpr float TWO_PI_F = 6.28318530717958647692f;
static constexpr float KE_F = 14.3996f;
static constexpr float ALPHA_F = 0.35f;

__device__ __forceinline__ int brev7(int i) { return (int)(__brev((unsigned)i) >> 25); }

__device__ __forceinline__ void inv3x3(const float* c, float* inv, float* adet) {
    float a00 = c[0], a01 = c[1], a02 = c[2];
    float a10 = c[3], a11 = c[4], a12 = c[5];
    float a20 = c[6], a21 = c[7], a22 = c[8];
    float det = a00 * (a11 * a22 - a12 * a21) - a01 * (a10 * a22 - a12 * a20) +
                a02 * (a10 * a21 - a11 * a20);
    float id = 1.0f / det;
    inv[0] = (a11 * a22 - a12 * a21) * id;
    inv[1] = (a02 * a21 - a01 * a22) * id;
    inv[2] = (a01 * a12 - a02 * a11) * id;
    inv[3] = (a12 * a20 - a10 * a22) * id;
    inv[4] = (a00 * a22 - a02 * a20) * id;
    inv[5] = (a02 * a10 - a00 * a12) * id;
    inv[6] = (a10 * a21 - a11 * a20) * id;
    inv[7] = (a01 * a20 - a00 * a21) * id;
    inv[8] = (a00 * a11 - a01 * a10) * id;
    *adet = fabsf(det);
}

__device__ __forceinline__ void bspline4(float f, float* w, float* dw) {
    float f2 = f * f, f3 = f2 * f;
    float omf = 1.0f - f;
    w[0] = omf * omf * omf * (1.0f / 6.0f);
    w[1] = (3.0f * f3 - 6.0f * f2 + 4.0f) * (1.0f / 6.0f);
    w[2] = (-3.0f * f3 + 3.0f * f2 + 3.0f * f + 1.0f) * (1.0f / 6.0f);
    w[3] = f3 * (1.0f / 6.0f);
    dw[0] = -0.5f * omf * omf;
    dw[1] = 1.5f * f2 - 2.0f * f;
    dw[2] = -1.5f * f2 + f + 0.5f;
    dw[3] = 0.5f * f2;
}

__device__ __forceinline__ void atom_base(const float* __restrict__ pos, const float* inv,
                                          int i, int base[3], float fpart[3]) {
    float p0 = pos[3 * i], p1 = pos[3 * i + 1], p2 = pos[3 * i + 2];
#pragma unroll
    for (int d = 0; d < 3; d++) {
        float fr = p0 * inv[d] + p1 * inv[3 + d] + p2 * inv[6 + d];
        fr -= floorf(fr);
        float u = fr * (float)KDIM;
        float bs = floorf(u);
        fpart[d] = u - bs;
        int b = (int)bs;
        base[d] = b & (KDIM - 1);
    }
}

__device__ __forceinline__ void atom_setup(const float* __restrict__ pos, const float* inv,
                                           int i, float wgt[3][4], float dwg[3][4],
                                           int idx[3][4]) {
    int base[3];
    float fp[3];
    atom_base(pos, inv, i, base, fp);
#pragma unroll
    for (int d = 0; d < 3; d++) {
        bspline4(fp[d], wgt[d], dwg[d]);
#pragma unroll
        for (int j = 0; j < 4; j++) idx[d][j] = (base[d] - 3 + j + KDIM) & (KDIM - 1);
    }
}

// ---------------- binning: histogram + per-block sum(q^2) ----------------
__global__ __launch_bounds__(256) void hist_kernel(const float* __restrict__ pos,
                                                   const float* __restrict__ chg,
                                                   const float* __restrict__ cell,
                                                   int* __restrict__ counts,
                                                   float* __restrict__ q2_part, int n) {
    __shared__ float hred[4];
    int i = blockIdx.x * blockDim.x + threadIdx.x;
    float q2 = 0.0f;
    if (i < n) {
        float inv[9], det;
        inv3x3(cell, inv, &det);
        int base[3];
        float fp[3];
        atom_base(pos, inv, i, base, fp);
        int bid = ((base[0] >> 3) << 8) | ((base[1] >> 3) << 4) | (base[2] >> 3);
        atomicAdd(&counts[bid], 1);
        float qi = chg[i];
        q2 = qi * qi;
    }
#pragma unroll
    for (int off = 32; off; off >>= 1) q2 += __shfl_down(q2, off);
    if ((threadIdx.x & 63) == 0) hred[threadIdx.x >> 6] = q2;
    __syncthreads();
    if (threadIdx.x == 0) q2_part[blockIdx.x] = hred[0] + hred[1] + hred[2] + hred[3];
}

__global__ __launch_bounds__(256) void scan_kernel(const int* __restrict__ counts,
                                                   int* __restrict__ starts) {
    __shared__ int part[256];
    int tid = threadIdx.x;
    int local[NBINS / 256];
    int sum = 0;
#pragma unroll
    for (int k = 0; k < NBINS / 256; k++) {
        local[k] = counts[tid * (NBINS / 256) + k];
        sum += local[k];
    }
    part[tid] = sum;
    __syncthreads();
    if (tid == 0) {
        int acc = 0;
        for (int i = 0; i < 256; i++) {
            int t = part[i];
            part[i] = acc;
            acc += t;
        }
        starts[NBINS] = acc;
    }
    __syncthreads();
    int acc = part[tid];
#pragma unroll
    for (int k = 0; k < NBINS / 256; k++) {
        starts[tid * (NBINS / 256) + k] = acc;
        acc += local[k];
    }
}

// scatter: weights record (64B) in bin-sorted order
// record: [0..3]=q*wx, [4..7]=wy, [8..11]=wz, [12]=loc bits, [13..15]=pad
__global__ __launch_bounds__(256) void scatter_kernel(const float* __restrict__ pos,
                                                      const float* __restrict__ chg,
                                                      const float* __restrict__ cell,
                                                      const int* __restrict__ starts,
                                                      int* __restrict__ cursor,
                                                      float* __restrict__ records, int n) {
    int i = blockIdx.x * blockDim.x + threadIdx.x;
    if (i >= n) return;
    float inv[9], det;
    inv3x3(cell, inv, &det);
    int base[3];
    float fp[3];
    atom_base(pos, inv, i, base, fp);
    int bid = ((base[0] >> 3) << 8) | ((base[1] >> 3) << 4) | (base[2] >> 3);
    int slot = atomicAdd(&cursor[bid], 1) + starts[bid];
    float4* rec = (float4*)(records + (size_t)slot * 16);
    float w[4], dw[4];
    float qi = chg[i];
    bspline4(fp[0], w, dw);
    rec[0] = make_float4(qi * w[0], qi * w[1], qi * w[2], qi * w[3]);
    bspline4(fp[1], w, dw);
    rec[1] = make_float4(w[0], w[1], w[2], w[3]);
    bspline4(fp[2], w, dw);
    rec[2] = make_float4(w[0], w[1], w[2], w[3]);
    int loc = (base[0] & 7) | ((base[1] & 7) << 4) | ((base[2] & 7) << 8);
    rec[3] = make_float4(__int_as_float(loc), 0.0f, 0.0f, 0.0f);
}

// ------- spreading: per-wave PRIVATE tiles, NON-ATOMIC read+add+write ----------------
// One wave per atom at a time; lane = (j0,j1,j2) -> 64 distinct cells of that atom.
__global__ __launch_bounds__(256) void spread_bins_kernel(
    const float* __restrict__ records, const int* __restrict__ starts,
    float* __restrict__ tiles) {
    __shared__ float tile4[4 * TPAD];
    __shared__ float4 arec[CHUNK * 4];
    int tid = threadIdx.x;
    int bid = blockIdx.x;
    for (int i = tid; i < 4 * TPAD; i += 256) tile4[i] = 0.0f;
    int s = starts[bid], e = starts[bid + 1];
    int w = tid >> 6, l = tid & 63;
    int j0 = l >> 4, j1 = (l >> 2) & 3, j2 = l & 3;
    int joff = j0 * T2 + j1 * TILE_D + j2;
    float* mytile = tile4 + w * TPAD;
    for (int c0 = s; c0 < e; c0 += CHUNK) {
        int cnt = min(CHUNK, e - c0);
        __syncthreads();
        if (tid < cnt) {
            const float4* rp = (const float4*)records + (size_t)(c0 + tid) * 4;
            arec[tid * 4 + 0] = rp[0];
            arec[tid * 4 + 1] = rp[1];
            arec[tid * 4 + 2] = rp[2];
            arec[tid * 4 + 3] = rp[3];
        }
        __syncthreads();
        for (int a = w; a < cnt; a += 4) {
            const float* A = (const float*)&arec[a << 2];
            float val = A[j0] * A[4 + j1] * A[8 + j2];
            int lc = __float_as_int(A[12]);
            int tb = (lc & 15) * T2 + ((lc >> 4) & 15) * TILE_D + ((lc >> 8) & 15);
            mytile[tb + joff] += val;   // non-atomic: wave-private tile, distinct lanes
        }
    }
    __syncthreads();
    float* tout = tiles + (size_t)bid * TSTRIDE;
    for (int i = tid; i < TILE_N; i += 256)
        tout[i] = tile4[i] + tile4[TPAD + i] + tile4[2 * TPAD + i] + tile4[3 * TPAD + i];
}

// ---------------- wave FFTs: DIF (natural->scrambled), DIT (scrambled->natural) ------
__device__ __forceinline__ float2 cmul(float2 a, float cs, float sn) {
    return make_float2(a.x * cs - a.y * sn, a.x * sn + a.y * cs);
}

__device__ __forceinline__ void wave_fft128_dif(float2& v0, float2& v1, int l, float sign) {
    {
        float ang = sign * (PI_F / 64.0f) * (float)l;
        float sn, cs;
        __sincosf(ang, &sn, &cs);
        float2 d = make_float2(v0.x - v1.x, v0.y - v1.y);
        v0 = make_float2(v0.x + v1.x, v0.y + v1.y);
        v1 = cmul(d, cs, sn);
    }
#pragma unroll
    for (int m = 32; m >= 1; m >>= 1) {
        float ang = sign * (PI_F / (float)m) * (float)(l & (m - 1));
        float sn, cs;
        __sincosf(ang, &sn, &cs);
        bool hi = (l & m) != 0;
        float2 p0, p1;
        p0.x = __shfl_xor(v0.x, m);
        p0.y = __shfl_xor(v0.y, m);
        p1.x = __shfl_xor(v1.x, m);
        p1.y = __shfl_xor(v1.y, m);
        float2 a0 = hi ? cmul(make_float2(p0.x - v0.x, p0.y - v0.y), cs, sn)
                       : make_float2(v0.x + p0.x, v0.y + p0.y);
        float2 a1 = hi ? cmul(make_float2(p1.x - v1.x, p1.y - v1.y), cs, sn)
                       : make_float2(v1.x + p1.x, v1.y + p1.y);
        v0 = a0;
        v1 = a1;
    }
}

__device__ __forceinline__ void wave_fft128_dit(float2& v0, float2& v1, int l, float sign) {
#pragma unroll
    for (int m = 1; m <= 32; m <<= 1) {
        float2 p0, p1;
        p0.x = __shfl_xor(v0.x, m);
        p0.y = __shfl_xor(v0.y, m);
        p1.x = __shfl_xor(v1.x, m);
        p1.y = __shfl_xor(v1.y, m);
        float ang = sign * (PI_F / (float)m) * (float)(l & (m - 1));
        float sn, cs;
        __sincosf(ang, &sn, &cs);
        bool hi = (l & m) != 0;
        float2 o0 = hi ? v0 : p0, e0 = hi ? p0 : v0;
        float2 o1 = hi ? v1 : p1, e1 = hi ? p1 : v1;
        float2 t0 = cmul(o0, cs, sn);
        float2 t1 = cmul(o1, cs, sn);
        float s = hi ? -1.0f : 1.0f;
        v0 = make_float2(e0.x + s * t0.x, e0.y + s * t0.y);
        v1 = make_float2(e1.x + s * t1.x, e1.y + s * t1.y);
    }
    float ang = sign * (PI_F / 64.0f) * (float)l;
    float sn, cs;
    __sincosf(ang, &sn, &cs);
    float2 t = cmul(v1, cs, sn);
    float2 e = v0;
    v0 = make_float2(e.x + t.x, e.y + t.y);
    v1 = make_float2(e.x - t.x, e.y - t.y);
}

// ---- forward z FFT with tile merge fused in ----
__global__ __launch_bounds__(512) void fft_z_merge(const float* __restrict__ tiles,
                                                   float2* __restrict__ C) {
    int w = threadIdx.x >> 6, l = threadIdx.x & 63;
    int line = (blockIdx.x << 3) + w;
    int gx = line >> 7, gy = line & 127;
    int bx = gx >> 3, ox = gx & 7;
    int by = gy >> 3, oy = gy & 7;
    int nx = (ox >= 5) ? 2 : 1, ny = (oy >= 5) ? 2 : 1;
    int bxs[2] = {bx, (bx + 1) & 15}, lxs[2] = {ox + 3, ox - 5};
    int bys[2] = {by, (by + 1) & 15}, lys[2] = {oy + 3, oy - 5};
    float2 v0, v1;
#pragma unroll
    for (int h = 0; h < 2; h++) {
        int gz = l + (h << 6);
        int bz = gz >> 3, oz = gz & 7;
        int nz = (oz >= 5) ? 2 : 1;
        int bzs[2] = {bz, (bz + 1) & 15}, lzs[2] = {oz + 3, oz - 5};
        float v = 0.0f;
        for (int i = 0; i < nx; i++)
            for (int j = 0; j < ny; j++) {
                int bxy = (bxs[i] << 8) | (bys[j] << 4);
                int lo = lxs[i] * T2 + lys[j] * TILE_D;
                for (int k = 0; k < nz; k++)
                    v += tiles[(size_t)(bxy | bzs[k]) * TSTRIDE + lo + lzs[k]];
            }
        if (h == 0) v0 = make_float2(v, 0.0f);
        else v1 = make_float2(v, 0.0f);
    }
    wave_fft128_dif(v0, v1, l, -1.0f);
    int base = line << 7;
    C[base + l] = v0;
    C[base + l + 64] = v1;
}

// ---- inverse z FFT (DIT), writes real potential mesh as float ----
__global__ __launch_bounds__(512) void fft_z_phi(const float2* __restrict__ C,
                                                 float* __restrict__ phi) {
    int w = threadIdx.x >> 6, l = threadIdx.x & 63;
    int line = (blockIdx.x << 3) + w;
    int base = line << 7;
    float2 v0 = C[base + l];
    float2 v1 = C[base + l + 64];
    wave_fft128_dit(v0, v1, l, 1.0f);
    phi[base + l] = v0.x;
    phi[base + l + 64] = v1.x;
}

// ---- FFT along strided dim (y). DIF=1 fwd, DIF=0 inv. 16-z chunks, LDS transpose. ---
template <int DIF>
__global__ __launch_bounds__(512) void fft_t(float2* __restrict__ C, int LS, int OS,
                                             float sign) {
    __shared__ float2 lds[128 * ST];
    int tid = threadIdx.x;
    int p = blockIdx.x >> 3;
    int z0 = (blockIdx.x & 7) << 4;
    int base = p * OS + z0;
#pragma unroll
    for (int k = 0; k < 2; k++) {
        int e = tid + (k << 9);
        int ll = e >> 3, zq = e & 7;
        float4 f = ((const float4*)C)[(base >> 1) + ll * (LS >> 1) + zq];
        lds[ll * ST + 2 * zq] = make_float2(f.x, f.y);
        lds[ll * ST + 2 * zq + 1] = make_float2(f.z, f.w);
    }
    __syncthreads();
    int w = tid >> 6, l = tid & 63;
#pragma unroll
    for (int c = 0; c < 2; c++) {
        int zt = (w << 1) | c;
        float2 v0 = lds[l * ST + zt];
        float2 v1 = lds[(l + 64) * ST + zt];
        if (DIF) wave_fft128_dif(v0, v1, l, sign);
        else wave_fft128_dit(v0, v1, l, sign);
        lds[l * ST + zt] = v0;
        lds[(l + 64) * ST + zt] = v1;
    }
    __syncthreads();
#pragma unroll
    for (int k = 0; k < 2; k++) {
        int e = tid + (k << 9);
        int ll = e >> 3, zq = e & 7;
        float2 a = lds[ll * ST + 2 * zq];
        float2 b = lds[ll * ST + 2 * zq + 1];
        ((float4*)C)[(base >> 1) + ll * (LS >> 1) + zq] = make_float4(a.x, a.y, b.x, b.y);
    }
}

// ---------------- scrambled-order m and |b|^-2 tables ----------------
__device__ __forceinline__ float bmod2f(int x) {
    float th = (TWO_PI_F / (float)KDIM) * (float)x;
    float s1, c1, s2, c2;
    __sincosf(th, &s1, &c1);
    __sincosf(th + th, &s2, &c2);
    float dr = 0.16666667f + 0.66666667f * c1 + 0.16666667f * c2;
    float di = 0.66666667f * s1 + 0.16666667f * s2;
    float d2 = dr * dr + di * di;
    return 1.0f / fmaxf(d2, 1e-12f);
}

__global__ void tbl_kernel(float* __restrict__ mtblS, float* __restrict__ btblS) {
    int i = threadIdx.x;
    if (i < KDIM) {
        int r = brev7(i);
        mtblS[i] = (float)(r < 64 ? r : r - 128);
        btblS[i] = bmod2f(r);
    }
}

// --------- fused: fwd x-DIF + scale (scrambled order) + energy + inv x-DIT ---------
__global__ __launch_bounds__(512) void fft_x_scale(float2* __restrict__ C,
                                                   const float* __restrict__ cell,
                                                   const float* __restrict__ mtblS,
                                                   const float* __restrict__ btblS,
                                                   float* __restrict__ scale_part) {
    __shared__ float2 lds[128 * ST];
    __shared__ float red[8];
    const int LS = KDIM * KDIM, OS = KDIM;
    int tid = threadIdx.x;
    int p = blockIdx.x >> 3;            // y slot
    int z0 = (blockIdx.x & 7) << 4;     // z chunk
    int base = p * OS + z0;
#pragma unroll
    for (int k = 0; k < 2; k++) {
        int e = tid + (k << 9);
        int ll = e >> 3, zq = e & 7;
        float4 f = ((const float4*)C)[(base >> 1) + ll * (LS >> 1) + zq];
        lds[ll * ST + 2 * zq] = make_float2(f.x, f.y);
        lds[ll * ST + 2 * zq + 1] = make_float2(f.z, f.w);
    }
    __syncthreads();
    int w = tid >> 6, l = tid & 63;
    float inv[9], det;
    inv3x3(cell, inv, &det);
    float my = mtblS[p];
    float by = btblS[p];
    float contrib = 0.0f;
#pragma unroll
    for (int c = 0; c < 2; c++) {
        int zt = (w << 1) | c;
        float2 v0 = lds[l * ST + zt];
        float2 v1 = lds[(l + 64) * ST + zt];
        wave_fft128_dif(v0, v1, l, -1.0f);
        int z = z0 + zt;
        float mz = mtblS[z];
        float byz = by * btblS[z];
#pragma unroll
        for (int h = 0; h < 2; h++) {
            int xs = l + (h << 6);      // x slot
            float mx = mtblS[xs];
            float kx = TWO_PI_F * (mx * inv[0] + my * inv[1] + mz * inv[2]);
            float ky = TWO_PI_F * (mx * inv[3] + my * inv[4] + mz * inv[5]);
            float kz = TWO_PI_F * (mx * inv[6] + my * inv[7] + mz * inv[8]);
            float k2 = kx * kx + ky * ky + kz * kz;
            float A = 0.0f;
            if (k2 > 0.0f)
                A = __expf(-k2 / (4.0f * ALPHA_F * ALPHA_F)) / k2 * btblS[xs] * byz;
            float2& v = h ? v1 : v0;
            contrib += A * (v.x * v.x + v.y * v.y);
            v.x *= A;
            v.y *= A;
        }
        wave_fft128_dit(v0, v1, l, 1.0f);
        lds[l * ST + zt] = v0;
        lds[(l + 64) * ST + zt] = v1;
    }
#pragma unroll
    for (int off = 32; off; off >>= 1) contrib += __shfl_down(contrib, off);
    if (l == 0) red[w] = contrib;
    __syncthreads();
    if (tid == 0) {
        float v = 0.0f;
        for (int i = 0; i < 8; i++) v += red[i];
        scale_part[blockIdx.x] = v;
    }
#pragma unroll
    for (int k = 0; k < 2; k++) {
        int e = tid + (k << 9);
        int ll = e >> 3, zq = e & 7;
        float2 a = lds[ll * ST + 2 * zq];
        float2 b = lds[ll * ST + 2 * zq + 1];
        ((float4*)C)[(base >> 1) + ll * (LS >> 1) + zq] = make_float4(a.x, a.y, b.x, b.y);
    }
}

// ---------------- energy finalize ----------------
__global__ __launch_bounds__(256) void finalize_kernel(const float* __restrict__ scale_part,
                                                       const float* __restrict__ q2_part,
                                                       int nq2,
                                                       const float* __restrict__ cell,
                                                       float* __restrict__ out) {
    __shared__ double sd[256];
    int tid = threadIdx.x;
    double es = 0.0;
    for (int i = tid; i < NSCALE_BLK; i += 256) es += (double)scale_part[i];
    double q2 = 0.0;
    for (int i = tid; i < nq2; i += 256) q2 += (double)q2_part[i];
    sd[tid] = es;
    __syncthreads();
    for (int s = 128; s; s >>= 1) {
        if (tid < s) sd[tid] += sd[tid + s];
        __syncthreads();
    }
    double esum = sd[0];
    __syncthreads();
    sd[tid] = q2;
    __syncthreads();
    for (int s = 128; s; s >>= 1) {
        if (tid < s) sd[tid] += sd[tid + s];
        __syncthreads();
    }
    if (tid == 0) {
        float inv[9], det;
        inv3x3(cell, inv, &det);
        double c = (double)KE_F * 2.0 * 3.14159265358979323846 / (double)det;
        double e = c * esum -
                   (double)KE_F * (double)ALPHA_F / 1.7724538509055160273 * sd[0];
        out[0] = (float)e;
    }
}

// ---------------- force gather (atom-parallel, reads float phi mesh) ----------------
__global__ __launch_bounds__(256) void gather_kernel(const float* __restrict__ pos,
                                                     const float* __restrict__ chg,
                                                     const float* __restrict__ cell,
                                                     const float* __restrict__ phi,
                                                     float* __restrict__ out, int n) {
    int i = blockIdx.x * blockDim.x + threadIdx.x;
    if (i >= n) return;
    float inv[9], det;
    inv3x3(cell, inv, &det);
    float wgt[3][4], dwg[3][4];
    int idx[3][4];
    atom_setup(pos, inv, i, wgt, dwg, idx);
    float acc0 = 0.0f, acc1 = 0.0f, acc2 = 0.0f;
#pragma unroll
    for (int j0 = 0; j0 < 4; j0++) {
        int r0 = idx[0][j0] << 14;
        float wx = wgt[0][j0], dx = dwg[0][j0];
#pragma unroll
        for (int j1 = 0; j1 < 4; j1++) {
            int r1 = r0 + (idx[1][j1] << 7);
            float wy = wgt[1][j1], dy = dwg[1][j1];
            float c00 = wx * wy;
            float c01 = wx * dy;
            float c02 = dx * wy;
#pragma unroll
            for (int j2 = 0; j2 < 4; j2++) {
                float p = phi[r1 + idx[2][j2]];
                float wz = wgt[2][j2], dz = dwg[2][j2];
                acc0 += p * c02 * wz;
                acc1 += p * c01 * wz;
                acc2 += p * c00 * dz;
            }
        }
    }
    float qi = chg[i];
    float c = KE_F * TWO_PI_F / det;
    float fac = -2.0f * c * qi * (float)KDIM;
    out[1 + 3 * i + 0] = fac * (acc0 * inv[0] + acc1 * inv[1] + acc2 * inv[2]);
    out[1 + 3 * i + 1] = fac * (acc0 * inv[3] + acc1 * inv[4] + acc2 * inv[5]);
    out[1 + 3 * i + 2] = fac * (acc0 * inv[6] + acc1 * inv[7] + acc2 * inv[8]);
}

extern "C" void kernel_launch(void* const* d_in, const int* in_sizes, int n_in,
                              void* d_out, int out_size, void* d_ws, size_t ws_size,
                              hipStream_t stream) {
    const float* pos = (const float*)d_in[0];
    const float* chg = (const float*)d_in[1];
    const float* cell = (const float*)d_in[2];
    float* out = (float*)d_out;
    int n = in_sizes[1];
    int nb = (n + 255) / 256;

    char* w = (char*)d_ws;
    float2* C = (float2*)w;                       // 16.78 MB; records alias this
    size_t off = (size_t)NTOT * sizeof(float2);
    float* tiles = (float*)(w + off);             // 22.02 MB; phi aliases this
    off += (size_t)NBINS * TSTRIDE * sizeof(float);
    int* counts = (int*)(w + off);                // NBINS (zeroed)
    size_t zoff = off;
    off += NBINS * sizeof(int);
    int* cursor = (int*)(w + off);                // NBINS (zeroed)
    off += NBINS * sizeof(int);
    size_t zero_bytes = off - zoff;
    int* starts = (int*)(w + off);                // NBINS+1
    off += (NBINS + 1) * sizeof(int);
    float* scale_part = (float*)(w + off);        // NSCALE_BLK
    off += NSCALE_BLK * sizeof(float);
    float* q2_part = (float*)(w + off);           // nb
    off += (size_t)nb * sizeof(float);
    float* mtblS = (float*)(w + off);             // 128
    off += KDIM * sizeof(float);
    float* btblS = (float*)(w + off);             // 128

    float* records = (float*)C;                   // dead after spread_bins
    float* phi = (float*)tiles;                   // tiles dead after fft_z_merge

    hipMemsetAsync(w + zoff, 0, zero_bytes, stream);

    tbl_kernel<<<1, 128, 0, stream>>>(mtblS, btblS);
    hist_kernel<<<nb, 256, 0, stream>>>(pos, chg, cell, counts, q2_part, n);
    scan_kernel<<<1, 256, 0, stream>>>(counts, starts);
    scatter_kernel<<<nb, 256, 0, stream>>>(pos, chg, cell, starts, cursor, records, n);
    spread_bins_kernel<<<NBINS, 256, 0, stream>>>(records, starts, tiles);

    fft_z_merge<<<2048, 512, 0, stream>>>(tiles, C);                    // fwd z (DIF)
    fft_t<1><<<1024, 512, 0, stream>>>(C, KDIM, KDIM * KDIM, -1.0f);    // fwd y (DIF)
    fft_x_scale<<<NSCALE_BLK, 512, 0, stream>>>(C, cell, mtblS, btblS, scale_part);
    fft_t<0><<<1024, 512, 0, stream>>>(C, KDIM, KDIM * KDIM, 1.0f);     // inv y (DIT)
    fft_z_phi<<<2048, 512, 0, stream>>>(C, phi);                        // inv z (DIT)

    finalize_kernel<<<1, 256, 0, stream>>>(scale_part, q2_part, nb, cell, out);
    gather_kernel<<<nb, 256, 0, stream>>>(pos, chg, cell, phi, out, n);
}

// Round 8
// 160.013 us; speedup vs baseline: 1.9125x; 1.1118x over previous
//
#include <hip/hip_runtime.h>

#define KDIM 128
#define NTOT (KDIM * KDIM * KDIM)
#define BPD 16          // bins per dim
#define NBINS (BPD * BPD * BPD)
#define TILE_D 11       // 8 + 3 halo
#define T2 (TILE_D * TILE_D)
#define TILE_N (TILE_D * TILE_D * TILE_D)
#define TPAD 1332       // per-wave LDS tile stride (floats)
#define TSTRIDE 1344    // padded global tile stride (floats)
#define CHUNK 256
#define NSCALE_BLK 1024
#define ST 17           // LDS row stride (float2) for transpose stages

static constexpr float PI_F = 3.14159265358979323846f;
static constexpr float TWO_PI_F = 6.28318530717958647692f;
static constexpr float KE_F = 14.3996f;
static constexpr float ALPHA_F = 0.35f;

__device__ __forceinline__ int brev7(int i) { return (int)(__brev((unsigned)i) >> 25); }

__device__ __forceinline__ void inv3x3(const float* c, float* inv, float* adet) {
    float a00 = c[0], a01 = c[1], a02 = c[2];
    float a10 = c[3], a11 = c[4], a12 = c[5];
    float a20 = c[6], a21 = c[7], a22 = c[8];
    float det = a00 * (a11 * a22 - a12 * a21) - a01 * (a10 * a22 - a12 * a20) +
                a02 * (a10 * a21 - a11 * a20);
    float id = 1.0f / det;
    inv[0] = (a11 * a22 - a12 * a21) * id;
    inv[1] = (a02 * a21 - a01 * a22) * id;
    inv[2] = (a01 * a12 - a02 * a11) * id;
    inv[3] = (a12 * a20 - a10 * a22) * id;
    inv[4] = (a00 * a22 - a02 * a20) * id;
    inv[5] = (a02 * a10 - a00 * a12) * id;
    inv[6] = (a10 * a21 - a11 * a20) * id;
    inv[7] = (a01 * a20 - a00 * a21) * id;
    inv[8] = (a00 * a11 - a01 * a10) * id;
    *adet = fabsf(det);
}

__device__ __forceinline__ void bspline4(float f, float* w, float* dw) {
    float f2 = f * f, f3 = f2 * f;
    float omf = 1.0f - f;
    w[0] = omf * omf * omf * (1.0f / 6.0f);
    w[1] = (3.0f * f3 - 6.0f * f2 + 4.0f) * (1.0f / 6.0f);
    w[2] = (-3.0f * f3 + 3.0f * f2 + 3.0f * f + 1.0f) * (1.0f / 6.0f);
    w[3] = f3 * (1.0f / 6.0f);
    dw[0] = -0.5f * omf * omf;
    dw[1] = 1.5f * f2 - 2.0f * f;
    dw[2] = -1.5f * f2 + f + 0.5f;
    dw[3] = 0.5f * f2;
}

__device__ __forceinline__ void atom_base(const float* __restrict__ pos, const float* inv,
                                          int i, int base[3], float fpart[3]) {
    float p0 = pos[3 * i], p1 = pos[3 * i + 1], p2 = pos[3 * i + 2];
#pragma unroll
    for (int d = 0; d < 3; d++) {
        float fr = p0 * inv[d] + p1 * inv[3 + d] + p2 * inv[6 + d];
        fr -= floorf(fr);
        float u = fr * (float)KDIM;
        float bs = floorf(u);
        fpart[d] = u - bs;
        int b = (int)bs;
        base[d] = b & (KDIM - 1);
    }
}

__device__ __forceinline__ void atom_setup(const float* __restrict__ pos, const float* inv,
                                           int i, float wgt[3][4], float dwg[3][4],
                                           int idx[3][4]) {
    int base[3];
    float fp[3];
    atom_base(pos, inv, i, base, fp);
#pragma unroll
    for (int d = 0; d < 3; d++) {
        bspline4(fp[d], wgt[d], dwg[d]);
#pragma unroll
        for (int j = 0; j < 4; j++) idx[d][j] = (base[d] - 3 + j + KDIM) & (KDIM - 1);
    }
}

// ---------------- binning: histogram + per-block sum(q^2) ----------------
__global__ __launch_bounds__(256) void hist_kernel(const float* __restrict__ pos,
                                                   const float* __restrict__ chg,
                                                   const float* __restrict__ cell,
                                                   int* __restrict__ counts,
                                                   float* __restrict__ q2_part, int n) {
    __shared__ float hred[4];
    int i = blockIdx.x * blockDim.x + threadIdx.x;
    float q2 = 0.0f;
    if (i < n) {
        float inv[9], det;
        inv3x3(cell, inv, &det);
        int base[3];
        float fp[3];
        atom_base(pos, inv, i, base, fp);
        int bid = ((base[0] >> 3) << 8) | ((base[1] >> 3) << 4) | (base[2] >> 3);
        atomicAdd(&counts[bid], 1);
        float qi = chg[i];
        q2 = qi * qi;
    }
#pragma unroll
    for (int off = 32; off; off >>= 1) q2 += __shfl_down(q2, off);
    if ((threadIdx.x & 63) == 0) hred[threadIdx.x >> 6] = q2;
    __syncthreads();
    if (threadIdx.x == 0) q2_part[blockIdx.x] = hred[0] + hred[1] + hred[2] + hred[3];
}

__global__ __launch_bounds__(256) void scan_kernel(const int* __restrict__ counts,
                                                   int* __restrict__ starts) {
    __shared__ int part[256];
    int tid = threadIdx.x;
    int local[NBINS / 256];
    int sum = 0;
#pragma unroll
    for (int k = 0; k < NBINS / 256; k++) {
        local[k] = counts[tid * (NBINS / 256) + k];
        sum += local[k];
    }
    part[tid] = sum;
    __syncthreads();
    if (tid == 0) {
        int acc = 0;
        for (int i = 0; i < 256; i++) {
            int t = part[i];
            part[i] = acc;
            acc += t;
        }
        starts[NBINS] = acc;
    }
    __syncthreads();
    int acc = part[tid];
#pragma unroll
    for (int k = 0; k < NBINS / 256; k++) {
        starts[tid * (NBINS / 256) + k] = acc;
        acc += local[k];
    }
}

// scatter: weights record (64B) in bin-sorted order + atom id list
// record: [0..3]=q*wx, [4..7]=wy, [8..11]=wz, [12]=loc bits, [13..15]=pad
__global__ __launch_bounds__(256) void scatter_kernel(const float* __restrict__ pos,
                                                      const float* __restrict__ chg,
                                                      const float* __restrict__ cell,
                                                      const int* __restrict__ starts,
                                                      int* __restrict__ cursor,
                                                      float* __restrict__ records,
                                                      int* __restrict__ binatoms, int n) {
    int i = blockIdx.x * blockDim.x + threadIdx.x;
    if (i >= n) return;
    float inv[9], det;
    inv3x3(cell, inv, &det);
    int base[3];
    float fp[3];
    atom_base(pos, inv, i, base, fp);
    int bid = ((base[0] >> 3) << 8) | ((base[1] >> 3) << 4) | (base[2] >> 3);
    int slot = atomicAdd(&cursor[bid], 1) + starts[bid];
    binatoms[slot] = i;
    float4* rec = (float4*)(records + (size_t)slot * 16);
    float w[4], dw[4];
    float qi = chg[i];
    bspline4(fp[0], w, dw);
    rec[0] = make_float4(qi * w[0], qi * w[1], qi * w[2], qi * w[3]);
    bspline4(fp[1], w, dw);
    rec[1] = make_float4(w[0], w[1], w[2], w[3]);
    bspline4(fp[2], w, dw);
    rec[2] = make_float4(w[0], w[1], w[2], w[3]);
    int loc = (base[0] & 7) | ((base[1] & 7) << 4) | ((base[2] & 7) << 8);
    rec[3] = make_float4(__int_as_float(loc), 0.0f, 0.0f, 0.0f);
}

// ------- spreading: per-wave PRIVATE tiles, NON-ATOMIC read+add+write ----------------
__global__ __launch_bounds__(256) void spread_bins_kernel(
    const float* __restrict__ records, const int* __restrict__ starts,
    float* __restrict__ tiles) {
    __shared__ float tile4[4 * TPAD];
    __shared__ float4 arec[CHUNK * 4];
    int tid = threadIdx.x;
    int bid = blockIdx.x;
    for (int i = tid; i < 4 * TPAD; i += 256) tile4[i] = 0.0f;
    int s = starts[bid], e = starts[bid + 1];
    int w = tid >> 6, l = tid & 63;
    int j0 = l >> 4, j1 = (l >> 2) & 3, j2 = l & 3;
    int joff = j0 * T2 + j1 * TILE_D + j2;
    float* mytile = tile4 + w * TPAD;
    for (int c0 = s; c0 < e; c0 += CHUNK) {
        int cnt = min(CHUNK, e - c0);
        __syncthreads();
        if (tid < cnt) {
            const float4* rp = (const float4*)records + (size_t)(c0 + tid) * 4;
            arec[tid * 4 + 0] = rp[0];
            arec[tid * 4 + 1] = rp[1];
            arec[tid * 4 + 2] = rp[2];
            arec[tid * 4 + 3] = rp[3];
        }
        __syncthreads();
        for (int a = w; a < cnt; a += 4) {
            const float* A = (const float*)&arec[a << 2];
            float val = A[j0] * A[4 + j1] * A[8 + j2];
            int lc = __float_as_int(A[12]);
            int tb = (lc & 15) * T2 + ((lc >> 4) & 15) * TILE_D + ((lc >> 8) & 15);
            mytile[tb + joff] += val;   // non-atomic: wave-private tile, distinct lanes
        }
    }
    __syncthreads();
    float* tout = tiles + (size_t)bid * TSTRIDE;
    for (int i = tid; i < TILE_N; i += 256)
        tout[i] = tile4[i] + tile4[TPAD + i] + tile4[2 * TPAD + i] + tile4[3 * TPAD + i];
}

// ---------------- wave FFTs: DIF (natural->scrambled), DIT (scrambled->natural) ------
__device__ __forceinline__ float2 cmul(float2 a, float cs, float sn) {
    return make_float2(a.x * cs - a.y * sn, a.x * sn + a.y * cs);
}

__device__ __forceinline__ void wave_fft128_dif(float2& v0, float2& v1, int l, float sign) {
    {
        float ang = sign * (PI_F / 64.0f) * (float)l;
        float sn, cs;
        __sincosf(ang, &sn, &cs);
        float2 d = make_float2(v0.x - v1.x, v0.y - v1.y);
        v0 = make_float2(v0.x + v1.x, v0.y + v1.y);
        v1 = cmul(d, cs, sn);
    }
#pragma unroll
    for (int m = 32; m >= 1; m >>= 1) {
        float ang = sign * (PI_F / (float)m) * (float)(l & (m - 1));
        float sn, cs;
        __sincosf(ang, &sn, &cs);
        bool hi = (l & m) != 0;
        float2 p0, p1;
        p0.x = __shfl_xor(v0.x, m);
        p0.y = __shfl_xor(v0.y, m);
        p1.x = __shfl_xor(v1.x, m);
        p1.y = __shfl_xor(v1.y, m);
        float2 a0 = hi ? cmul(make_float2(p0.x - v0.x, p0.y - v0.y), cs, sn)
                       : make_float2(v0.x + p0.x, v0.y + p0.y);
        float2 a1 = hi ? cmul(make_float2(p1.x - v1.x, p1.y - v1.y), cs, sn)
                       : make_float2(v1.x + p1.x, v1.y + p1.y);
        v0 = a0;
        v1 = a1;
    }
}

__device__ __forceinline__ void wave_fft128_dit(float2& v0, float2& v1, int l, float sign) {
#pragma unroll
    for (int m = 1; m <= 32; m <<= 1) {
        float2 p0, p1;
        p0.x = __shfl_xor(v0.x, m);
        p0.y = __shfl_xor(v0.y, m);
        p1.x = __shfl_xor(v1.x, m);
        p1.y = __shfl_xor(v1.y, m);
        float ang = sign * (PI_F / (float)m) * (float)(l & (m - 1));
        float sn, cs;
        __sincosf(ang, &sn, &cs);
        bool hi = (l & m) != 0;
        float2 o0 = hi ? v0 : p0, e0 = hi ? p0 : v0;
        float2 o1 = hi ? v1 : p1, e1 = hi ? p1 : v1;
        float2 t0 = cmul(o0, cs, sn);
        float2 t1 = cmul(o1, cs, sn);
        float s = hi ? -1.0f : 1.0f;
        v0 = make_float2(e0.x + s * t0.x, e0.y + s * t0.y);
        v1 = make_float2(e1.x + s * t1.x, e1.y + s * t1.y);
    }
    float ang = sign * (PI_F / 64.0f) * (float)l;
    float sn, cs;
    __sincosf(ang, &sn, &cs);
    float2 t = cmul(v1, cs, sn);
    float2 e = v0;
    v0 = make_float2(e.x + t.x, e.y + t.y);
    v1 = make_float2(e.x - t.x, e.y - t.y);
}

// ---- forward z FFT with tile merge fused in ----
__global__ __launch_bounds__(512) void fft_z_merge(const float* __restrict__ tiles,
                                                   float2* __restrict__ C) {
    int w = threadIdx.x >> 6, l = threadIdx.x & 63;
    int line = (blockIdx.x << 3) + w;
    int gx = line >> 7, gy = line & 127;
    int bx = gx >> 3, ox = gx & 7;
    int by = gy >> 3, oy = gy & 7;
    int nx = (ox >= 5) ? 2 : 1, ny = (oy >= 5) ? 2 : 1;
    int bxs[2] = {bx, (bx + 1) & 15}, lxs[2] = {ox + 3, ox - 5};
    int bys[2] = {by, (by + 1) & 15}, lys[2] = {oy + 3, oy - 5};
    float2 v0, v1;
#pragma unroll
    for (int h = 0; h < 2; h++) {
        int gz = l + (h << 6);
        int bz = gz >> 3, oz = gz & 7;
        int nz = (oz >= 5) ? 2 : 1;
        int bzs[2] = {bz, (bz + 1) & 15}, lzs[2] = {oz + 3, oz - 5};
        float v = 0.0f;
        for (int i = 0; i < nx; i++)
            for (int j = 0; j < ny; j++) {
                int bxy = (bxs[i] << 8) | (bys[j] << 4);
                int lo = lxs[i] * T2 + lys[j] * TILE_D;
                for (int k = 0; k < nz; k++)
                    v += tiles[(size_t)(bxy | bzs[k]) * TSTRIDE + lo + lzs[k]];
            }
        if (h == 0) v0 = make_float2(v, 0.0f);
        else v1 = make_float2(v, 0.0f);
    }
    wave_fft128_dif(v0, v1, l, -1.0f);
    int base = line << 7;
    C[base + l] = v0;
    C[base + l + 64] = v1;
}

// ---- inverse z FFT (DIT), writes real potential mesh as float ----
__global__ __launch_bounds__(512) void fft_z_phi(const float2* __restrict__ C,
                                                 float* __restrict__ phi) {
    int w = threadIdx.x >> 6, l = threadIdx.x & 63;
    int line = (blockIdx.x << 3) + w;
    int base = line << 7;
    float2 v0 = C[base + l];
    float2 v1 = C[base + l + 64];
    wave_fft128_dit(v0, v1, l, 1.0f);
    phi[base + l] = v0.x;
    phi[base + l + 64] = v1.x;
}

// ---- FFT along strided dim (y). DIF=1 fwd, DIF=0 inv. 16-z chunks, LDS transpose. ---
template <int DIF>
__global__ __launch_bounds__(512) void fft_t(float2* __restrict__ C, int LS, int OS,
                                             float sign) {
    __shared__ float2 lds[128 * ST];
    int tid = threadIdx.x;
    int p = blockIdx.x >> 3;
    int z0 = (blockIdx.x & 7) << 4;
    int base = p * OS + z0;
#pragma unroll
    for (int k = 0; k < 2; k++) {
        int e = tid + (k << 9);
        int ll = e >> 3, zq = e & 7;
        float4 f = ((const float4*)C)[(base >> 1) + ll * (LS >> 1) + zq];
        lds[ll * ST + 2 * zq] = make_float2(f.x, f.y);
        lds[ll * ST + 2 * zq + 1] = make_float2(f.z, f.w);
    }
    __syncthreads();
    int w = tid >> 6, l = tid & 63;
#pragma unroll
    for (int c = 0; c < 2; c++) {
        int zt = (w << 1) | c;
        float2 v0 = lds[l * ST + zt];
        float2 v1 = lds[(l + 64) * ST + zt];
        if (DIF) wave_fft128_dif(v0, v1, l, sign);
        else wave_fft128_dit(v0, v1, l, sign);
        lds[l * ST + zt] = v0;
        lds[(l + 64) * ST + zt] = v1;
    }
    __syncthreads();
#pragma unroll
    for (int k = 0; k < 2; k++) {
        int e = tid + (k << 9);
        int ll = e >> 3, zq = e & 7;
        float2 a = lds[ll * ST + 2 * zq];
        float2 b = lds[ll * ST + 2 * zq + 1];
        ((float4*)C)[(base >> 1) + ll * (LS >> 1) + zq] = make_float4(a.x, a.y, b.x, b.y);
    }
}

// ---------------- scrambled-order m and |b|^-2 tables ----------------
__device__ __forceinline__ float bmod2f(int x) {
    float th = (TWO_PI_F / (float)KDIM) * (float)x;
    float s1, c1, s2, c2;
    __sincosf(th, &s1, &c1);
    __sincosf(th + th, &s2, &c2);
    float dr = 0.16666667f + 0.66666667f * c1 + 0.16666667f * c2;
    float di = 0.66666667f * s1 + 0.16666667f * s2;
    float d2 = dr * dr + di * di;
    return 1.0f / fmaxf(d2, 1e-12f);
}

__global__ void tbl_kernel(float* __restrict__ mtblS, float* __restrict__ btblS) {
    int i = threadIdx.x;
    if (i < KDIM) {
        int r = brev7(i);
        mtblS[i] = (float)(r < 64 ? r : r - 128);
        btblS[i] = bmod2f(r);
    }
}

// --------- fused: fwd x-DIF + scale (scrambled order) + energy + inv x-DIT ---------
__global__ __launch_bounds__(512) void fft_x_scale(float2* __restrict__ C,
                                                   const float* __restrict__ cell,
                                                   const float* __restrict__ mtblS,
                                                   const float* __restrict__ btblS,
                                                   float* __restrict__ scale_part) {
    __shared__ float2 lds[128 * ST];
    __shared__ float red[8];
    const int LS = KDIM * KDIM, OS = KDIM;
    int tid = threadIdx.x;
    int p = blockIdx.x >> 3;            // y slot
    int z0 = (blockIdx.x & 7) << 4;     // z chunk
    int base = p * OS + z0;
#pragma unroll
    for (int k = 0; k < 2; k++) {
        int e = tid + (k << 9);
        int ll = e >> 3, zq = e & 7;
        float4 f = ((const float4*)C)[(base >> 1) + ll * (LS >> 1) + zq];
        lds[ll * ST + 2 * zq] = make_float2(f.x, f.y);
        lds[ll * ST + 2 * zq + 1] = make_float2(f.z, f.w);
    }
    __syncthreads();
    int w = tid >> 6, l = tid & 63;
    float inv[9], det;
    inv3x3(cell, inv, &det);
    float my = mtblS[p];
    float by = btblS[p];
    float contrib = 0.0f;
#pragma unroll
    for (int c = 0; c < 2; c++) {
        int zt = (w << 1) | c;
        float2 v0 = lds[l * ST + zt];
        float2 v1 = lds[(l + 64) * ST + zt];
        wave_fft128_dif(v0, v1, l, -1.0f);
        int z = z0 + zt;
        float mz = mtblS[z];
        float byz = by * btblS[z];
#pragma unroll
        for (int h = 0; h < 2; h++) {
            int xs = l + (h << 6);      // x slot
            float mx = mtblS[xs];
            float kx = TWO_PI_F * (mx * inv[0] + my * inv[1] + mz * inv[2]);
            float ky = TWO_PI_F * (mx * inv[3] + my * inv[4] + mz * inv[5]);
            float kz = TWO_PI_F * (mx * inv[6] + my * inv[7] + mz * inv[8]);
            float k2 = kx * kx + ky * ky + kz * kz;
            float A = 0.0f;
            if (k2 > 0.0f)
                A = __expf(-k2 / (4.0f * ALPHA_F * ALPHA_F)) / k2 * btblS[xs] * byz;
            float2& v = h ? v1 : v0;
            contrib += A * (v.x * v.x + v.y * v.y);
            v.x *= A;
            v.y *= A;
        }
        wave_fft128_dit(v0, v1, l, 1.0f);
        lds[l * ST + zt] = v0;
        lds[(l + 64) * ST + zt] = v1;
    }
#pragma unroll
    for (int off = 32; off; off >>= 1) contrib += __shfl_down(contrib, off);
    if (l == 0) red[w] = contrib;
    __syncthreads();
    if (tid == 0) {
        float v = 0.0f;
        for (int i = 0; i < 8; i++) v += red[i];
        scale_part[blockIdx.x] = v;
    }
#pragma unroll
    for (int k = 0; k < 2; k++) {
        int e = tid + (k << 9);
        int ll = e >> 3, zq = e & 7;
        float2 a = lds[ll * ST + 2 * zq];
        float2 b = lds[ll * ST + 2 * zq + 1];
        ((float4*)C)[(base >> 1) + ll * (LS >> 1) + zq] = make_float4(a.x, a.y, b.x, b.y);
    }
}

// ---------------- energy finalize ----------------
__global__ __launch_bounds__(256) void finalize_kernel(const float* __restrict__ scale_part,
                                                       const float* __restrict__ q2_part,
                                                       int nq2,
                                                       const float* __restrict__ cell,
                                                       float* __restrict__ out) {
    __shared__ double sd[256];
    int tid = threadIdx.x;
    double es = 0.0;
    for (int i = tid; i < NSCALE_BLK; i += 256) es += (double)scale_part[i];
    double q2 = 0.0;
    for (int i = tid; i < nq2; i += 256) q2 += (double)q2_part[i];
    sd[tid] = es;
    __syncthreads();
    for (int s = 128; s; s >>= 1) {
        if (tid < s) sd[tid] += sd[tid + s];
        __syncthreads();
    }
    double esum = sd[0];
    __syncthreads();
    sd[tid] = q2;
    __syncthreads();
    for (int s = 128; s; s >>= 1) {
        if (tid < s) sd[tid] += sd[tid + s];
        __syncthreads();
    }
    if (tid == 0) {
        float inv[9], det;
        inv3x3(cell, inv, &det);
        double c = (double)KE_F * 2.0 * 3.14159265358979323846 / (double)det;
        double e = c * esum -
                   (double)KE_F * (double)ALPHA_F / 1.7724538509055160273 * sd[0];
        out[0] = (float)e;
    }
}

// ------- force gather: atoms processed in bin-sorted order for mesh L2 locality ------
__global__ __launch_bounds__(256) void gather_kernel(const float* __restrict__ pos,
                                                     const float* __restrict__ chg,
                                                     const float* __restrict__ cell,
                                                     const int* __restrict__ binatoms,
                                                     const float* __restrict__ phi,
                                                     float* __restrict__ out, int n) {
    int a = blockIdx.x * blockDim.x + threadIdx.x;
    if (a >= n) return;
    int i = binatoms[a];
    float inv[9], det;
    inv3x3(cell, inv, &det);
    float wgt[3][4], dwg[3][4];
    int idx[3][4];
    atom_setup(pos, inv, i, wgt, dwg, idx);
    float acc0 = 0.0f, acc1 = 0.0f, acc2 = 0.0f;
#pragma unroll
    for (int j0 = 0; j0 < 4; j0++) {
        int r0 = idx[0][j0] << 14;
        float wx = wgt[0][j0], dx = dwg[0][j0];
#pragma unroll
        for (int j1 = 0; j1 < 4; j1++) {
            int r1 = r0 + (idx[1][j1] << 7);
            float wy = wgt[1][j1], dy = dwg[1][j1];
            float c00 = wx * wy;
            float c01 = wx * dy;
            float c02 = dx * wy;
#pragma unroll
            for (int j2 = 0; j2 < 4; j2++) {
                float p = phi[r1 + idx[2][j2]];
                float wz = wgt[2][j2], dz = dwg[2][j2];
                acc0 += p * c02 * wz;
                acc1 += p * c01 * wz;
                acc2 += p * c00 * dz;
            }
        }
    }
    float qi = chg[i];
    float c = KE_F * TWO_PI_F / det;
    float fac = -2.0f * c * qi * (float)KDIM;
    out[1 + 3 * i + 0] = fac * (acc0 * inv[0] + acc1 * inv[1] + acc2 * inv[2]);
    out[1 + 3 * i + 1] = fac * (acc0 * inv[3] + acc1 * inv[4] + acc2 * inv[5]);
    out[1 + 3 * i + 2] = fac * (acc0 * inv[6] + acc1 * inv[7] + acc2 * inv[8]);
}

extern "C" void kernel_launch(void* const* d_in, const int* in_sizes, int n_in,
                              void* d_out, int out_size, void* d_ws, size_t ws_size,
                              hipStream_t stream) {
    const float* pos = (const float*)d_in[0];
    const float* chg = (const float*)d_in[1];
    const float* cell = (const float*)d_in[2];
    float* out = (float*)d_out;
    int n = in_sizes[1];
    int nb = (n + 255) / 256;

    char* w = (char*)d_ws;
    float2* C = (float2*)w;                       // 16.78 MB; records alias this
    size_t off = (size_t)NTOT * sizeof(float2);
    float* tiles = (float*)(w + off);             // 22.02 MB; phi aliases this
    off += (size_t)NBINS * TSTRIDE * sizeof(float);
    int* counts = (int*)(w + off);                // NBINS (zeroed)
    size_t zoff = off;
    off += NBINS * sizeof(int);
    int* cursor = (int*)(w + off);                // NBINS (zeroed)
    off += NBINS * sizeof(int);
    size_t zero_bytes = off - zoff;
    int* starts = (int*)(w + off);                // NBINS+1
    off += (NBINS + 1) * sizeof(int);
    int* binatoms = (int*)(w + off);              // n
    off += (size_t)n * sizeof(int);
    float* scale_part = (float*)(w + off);        // NSCALE_BLK
    off += NSCALE_BLK * sizeof(float);
    float* q2_part = (float*)(w + off);           // nb
    off += (size_t)nb * sizeof(float);
    float* mtblS = (float*)(w + off);             // 128
    off += KDIM * sizeof(float);
    float* btblS = (float*)(w + off);             // 128

    float* records = (float*)C;                   // dead after spread_bins
    float* phi = (float*)tiles;                   // tiles dead after fft_z_merge

    hipMemsetAsync(w + zoff, 0, zero_bytes, stream);

    tbl_kernel<<<1, 128, 0, stream>>>(mtblS, btblS);
    hist_kernel<<<nb, 256, 0, stream>>>(pos, chg, cell, counts, q2_part, n);
    scan_kernel<<<1, 256, 0, stream>>>(counts, starts);
    scatter_kernel<<<nb, 256, 0, stream>>>(pos, chg, cell, starts, cursor, records,
                                           binatoms, n);
    spread_bins_kernel<<<NBINS, 256, 0, stream>>>(records, starts, tiles);

    fft_z_merge<<<2048, 512, 0, stream>>>(tiles, C);                    // fwd z (DIF)
    fft_t<1><<<1024, 512, 0, stream>>>(C, KDIM, KDIM * KDIM, -1.0f);    // fwd y (DIF)
    fft_x_scale<<<NSCALE_BLK, 512, 0, stream>>>(C, cell, mtblS, btblS, scale_part);
    fft_t<0><<<1024, 512, 0, stream>>>(C, KDIM, KDIM * KDIM, 1.0f);     // inv y (DIT)
    fft_z_phi<<<2048, 512, 0, stream>>>(C, phi);                        // inv z (DIT)

    finalize_kernel<<<1, 256, 0, stream>>>(scale_part, q2_part, nb, cell, out);
    gather_kernel<<<nb, 256, 0, stream>>>(pos, chg, cell, binatoms, phi, out, n);
}

// Round 9
// 159.839 us; speedup vs baseline: 1.9146x; 1.0011x over previous
//
#include <hip/hip_runtime.h>

#define KDIM 128
#define NTOT (KDIM * KDIM * KDIM)
#define BPD 16          // bins per dim
#define NBINS (BPD * BPD * BPD)
#define TILE_D 11       // 8 + 3 halo
#define T2 (TILE_D * TILE_D)
#define TILE_N (TILE_D * TILE_D * TILE_D)
#define TPAD 1332       // per-wave LDS tile stride (floats)
#define TSTRIDE 1344    // padded global tile stride (floats)
#define CHUNK 256
#define NSCALE_BLK 1024
#define ST 17           // LDS row stride (float2) for transpose stages

static constexpr float PI_F = 3.14159265358979323846f;
static constexpr float TWO_PI_F = 6.28318530717958647692f;
static constexpr float KE_F = 14.3996f;
static constexpr float ALPHA_F = 0.35f;

__device__ __forceinline__ int brev7(int i) { return (int)(__brev((unsigned)i) >> 25); }

__device__ __forceinline__ void inv3x3(const float* c, float* inv, float* adet) {
    float a00 = c[0], a01 = c[1], a02 = c[2];
    float a10 = c[3], a11 = c[4], a12 = c[5];
    float a20 = c[6], a21 = c[7], a22 = c[8];
    float det = a00 * (a11 * a22 - a12 * a21) - a01 * (a10 * a22 - a12 * a20) +
                a02 * (a10 * a21 - a11 * a20);
    float id = 1.0f / det;
    inv[0] = (a11 * a22 - a12 * a21) * id;
    inv[1] = (a02 * a21 - a01 * a22) * id;
    inv[2] = (a01 * a12 - a02 * a11) * id;
    inv[3] = (a12 * a20 - a10 * a22) * id;
    inv[4] = (a00 * a22 - a02 * a20) * id;
    inv[5] = (a02 * a10 - a00 * a12) * id;
    inv[6] = (a10 * a21 - a11 * a20) * id;
    inv[7] = (a01 * a20 - a00 * a21) * id;
    inv[8] = (a00 * a11 - a01 * a10) * id;
    *adet = fabsf(det);
}

__device__ __forceinline__ void bspline4(float f, float* w, float* dw) {
    float f2 = f * f, f3 = f2 * f;
    float omf = 1.0f - f;
    w[0] = omf * omf * omf * (1.0f / 6.0f);
    w[1] = (3.0f * f3 - 6.0f * f2 + 4.0f) * (1.0f / 6.0f);
    w[2] = (-3.0f * f3 + 3.0f * f2 + 3.0f * f + 1.0f) * (1.0f / 6.0f);
    w[3] = f3 * (1.0f / 6.0f);
    dw[0] = -0.5f * omf * omf;
    dw[1] = 1.5f * f2 - 2.0f * f;
    dw[2] = -1.5f * f2 + f + 0.5f;
    dw[3] = 0.5f * f2;
}

__device__ __forceinline__ void atom_base(const float* __restrict__ pos, const float* inv,
                                          int i, int base[3], float fpart[3]) {
    float p0 = pos[3 * i], p1 = pos[3 * i + 1], p2 = pos[3 * i + 2];
#pragma unroll
    for (int d = 0; d < 3; d++) {
        float fr = p0 * inv[d] + p1 * inv[3 + d] + p2 * inv[6 + d];
        fr -= floorf(fr);
        float u = fr * (float)KDIM;
        float bs = floorf(u);
        fpart[d] = u - bs;
        int b = (int)bs;
        base[d] = b & (KDIM - 1);
    }
}

__device__ __forceinline__ void atom_setup(const float* __restrict__ pos, const float* inv,
                                           int i, float wgt[3][4], float dwg[3][4],
                                           int idx[3][4]) {
    int base[3];
    float fp[3];
    atom_base(pos, inv, i, base, fp);
#pragma unroll
    for (int d = 0; d < 3; d++) {
        bspline4(fp[d], wgt[d], dwg[d]);
#pragma unroll
        for (int j = 0; j < 4; j++) idx[d][j] = (base[d] - 3 + j + KDIM) & (KDIM - 1);
    }
}

// ---------------- zero counts+cursor (replaces pathological hipMemsetAsync) ---------
__global__ __launch_bounds__(256) void zero_kernel(int* __restrict__ counts,
                                                   int* __restrict__ cursor) {
    int i = blockIdx.x * 256 + threadIdx.x;
    if (i < NBINS) {
        counts[i] = 0;
        cursor[i] = 0;
    }
}

// ---------------- binning: histogram + per-block sum(q^2) ----------------
__global__ __launch_bounds__(256) void hist_kernel(const float* __restrict__ pos,
                                                   const float* __restrict__ chg,
                                                   const float* __restrict__ cell,
                                                   int* __restrict__ counts,
                                                   float* __restrict__ q2_part, int n) {
    __shared__ float hred[4];
    int i = blockIdx.x * blockDim.x + threadIdx.x;
    float q2 = 0.0f;
    if (i < n) {
        float inv[9], det;
        inv3x3(cell, inv, &det);
        int base[3];
        float fp[3];
        atom_base(pos, inv, i, base, fp);
        int bid = ((base[0] >> 3) << 8) | ((base[1] >> 3) << 4) | (base[2] >> 3);
        atomicAdd(&counts[bid], 1);
        float qi = chg[i];
        q2 = qi * qi;
    }
#pragma unroll
    for (int off = 32; off; off >>= 1) q2 += __shfl_down(q2, off);
    if ((threadIdx.x & 63) == 0) hred[threadIdx.x >> 6] = q2;
    __syncthreads();
    if (threadIdx.x == 0) q2_part[blockIdx.x] = hred[0] + hred[1] + hred[2] + hred[3];
}

__global__ __launch_bounds__(256) void scan_kernel(const int* __restrict__ counts,
                                                   int* __restrict__ starts) {
    __shared__ int part[256];
    int tid = threadIdx.x;
    int local[NBINS / 256];
    int sum = 0;
#pragma unroll
    for (int k = 0; k < NBINS / 256; k++) {
        local[k] = counts[tid * (NBINS / 256) + k];
        sum += local[k];
    }
    part[tid] = sum;
    __syncthreads();
    if (tid == 0) {
        int acc = 0;
        for (int i = 0; i < 256; i++) {
            int t = part[i];
            part[i] = acc;
            acc += t;
        }
        starts[NBINS] = acc;
    }
    __syncthreads();
    int acc = part[tid];
#pragma unroll
    for (int k = 0; k < NBINS / 256; k++) {
        starts[tid * (NBINS / 256) + k] = acc;
        acc += local[k];
    }
}

// scatter: weights record (64B) in bin-sorted order + atom id list
// record: [0..3]=q*wx, [4..7]=wy, [8..11]=wz, [12]=loc bits, [13..15]=pad
__global__ __launch_bounds__(256) void scatter_kernel(const float* __restrict__ pos,
                                                      const float* __restrict__ chg,
                                                      const float* __restrict__ cell,
                                                      const int* __restrict__ starts,
                                                      int* __restrict__ cursor,
                                                      float* __restrict__ records,
                                                      int* __restrict__ binatoms, int n) {
    int i = blockIdx.x * blockDim.x + threadIdx.x;
    if (i >= n) return;
    float inv[9], det;
    inv3x3(cell, inv, &det);
    int base[3];
    float fp[3];
    atom_base(pos, inv, i, base, fp);
    int bid = ((base[0] >> 3) << 8) | ((base[1] >> 3) << 4) | (base[2] >> 3);
    int slot = atomicAdd(&cursor[bid], 1) + starts[bid];
    binatoms[slot] = i;
    float4* rec = (float4*)(records + (size_t)slot * 16);
    float w[4], dw[4];
    float qi = chg[i];
    bspline4(fp[0], w, dw);
    rec[0] = make_float4(qi * w[0], qi * w[1], qi * w[2], qi * w[3]);
    bspline4(fp[1], w, dw);
    rec[1] = make_float4(w[0], w[1], w[2], w[3]);
    bspline4(fp[2], w, dw);
    rec[2] = make_float4(w[0], w[1], w[2], w[3]);
    int loc = (base[0] & 7) | ((base[1] & 7) << 4) | ((base[2] & 7) << 8);
    rec[3] = make_float4(__int_as_float(loc), 0.0f, 0.0f, 0.0f);
}

// ------- spreading: per-wave PRIVATE tiles, NON-ATOMIC read+add+write ----------------
__global__ __launch_bounds__(256) void spread_bins_kernel(
    const float* __restrict__ records, const int* __restrict__ starts,
    float* __restrict__ tiles) {
    __shared__ float tile4[4 * TPAD];
    __shared__ float4 arec[CHUNK * 4];
    int tid = threadIdx.x;
    int bid = blockIdx.x;
    for (int i = tid; i < 4 * TPAD; i += 256) tile4[i] = 0.0f;
    int s = starts[bid], e = starts[bid + 1];
    int w = tid >> 6, l = tid & 63;
    int j0 = l >> 4, j1 = (l >> 2) & 3, j2 = l & 3;
    int joff = j0 * T2 + j1 * TILE_D + j2;
    float* mytile = tile4 + w * TPAD;
    for (int c0 = s; c0 < e; c0 += CHUNK) {
        int cnt = min(CHUNK, e - c0);
        __syncthreads();
        if (tid < cnt) {
            const float4* rp = (const float4*)records + (size_t)(c0 + tid) * 4;
            arec[tid * 4 + 0] = rp[0];
            arec[tid * 4 + 1] = rp[1];
            arec[tid * 4 + 2] = rp[2];
            arec[tid * 4 + 3] = rp[3];
        }
        __syncthreads();
        for (int a = w; a < cnt; a += 4) {
            const float* A = (const float*)&arec[a << 2];
            float val = A[j0] * A[4 + j1] * A[8 + j2];
            int lc = __float_as_int(A[12]);
            int tb = (lc & 15) * T2 + ((lc >> 4) & 15) * TILE_D + ((lc >> 8) & 15);
            mytile[tb + joff] += val;   // non-atomic: wave-private tile, distinct lanes
        }
    }
    __syncthreads();
    float* tout = tiles + (size_t)bid * TSTRIDE;
    for (int i = tid; i < TILE_N; i += 256)
        tout[i] = tile4[i] + tile4[TPAD + i] + tile4[2 * TPAD + i] + tile4[3 * TPAD + i];
}

// ---------------- wave FFTs: DIF (natural->scrambled), DIT (scrambled->natural) ------
__device__ __forceinline__ float2 cmul(float2 a, float cs, float sn) {
    return make_float2(a.x * cs - a.y * sn, a.x * sn + a.y * cs);
}

__device__ __forceinline__ void wave_fft128_dif(float2& v0, float2& v1, int l, float sign) {
    {
        float ang = sign * (PI_F / 64.0f) * (float)l;
        float sn, cs;
        __sincosf(ang, &sn, &cs);
        float2 d = make_float2(v0.x - v1.x, v0.y - v1.y);
        v0 = make_float2(v0.x + v1.x, v0.y + v1.y);
        v1 = cmul(d, cs, sn);
    }
#pragma unroll
    for (int m = 32; m >= 1; m >>= 1) {
        float ang = sign * (PI_F / (float)m) * (float)(l & (m - 1));
        float sn, cs;
        __sincosf(ang, &sn, &cs);
        bool hi = (l & m) != 0;
        float2 p0, p1;
        p0.x = __shfl_xor(v0.x, m);
        p0.y = __shfl_xor(v0.y, m);
        p1.x = __shfl_xor(v1.x, m);
        p1.y = __shfl_xor(v1.y, m);
        float2 a0 = hi ? cmul(make_float2(p0.x - v0.x, p0.y - v0.y), cs, sn)
                       : make_float2(v0.x + p0.x, v0.y + p0.y);
        float2 a1 = hi ? cmul(make_float2(p1.x - v1.x, p1.y - v1.y), cs, sn)
                       : make_float2(v1.x + p1.x, v1.y + p1.y);
        v0 = a0;
        v1 = a1;
    }
}

__device__ __forceinline__ void wave_fft128_dit(float2& v0, float2& v1, int l, float sign) {
#pragma unroll
    for (int m = 1; m <= 32; m <<= 1) {
        float2 p0, p1;
        p0.x = __shfl_xor(v0.x, m);
        p0.y = __shfl_xor(v0.y, m);
        p1.x = __shfl_xor(v1.x, m);
        p1.y = __shfl_xor(v1.y, m);
        float ang = sign * (PI_F / (float)m) * (float)(l & (m - 1));
        float sn, cs;
        __sincosf(ang, &sn, &cs);
        bool hi = (l & m) != 0;
        float2 o0 = hi ? v0 : p0, e0 = hi ? p0 : v0;
        float2 o1 = hi ? v1 : p1, e1 = hi ? p1 : v1;
        float2 t0 = cmul(o0, cs, sn);
        float2 t1 = cmul(o1, cs, sn);
        float s = hi ? -1.0f : 1.0f;
        v0 = make_float2(e0.x + s * t0.x, e0.y + s * t0.y);
        v1 = make_float2(e1.x + s * t1.x, e1.y + s * t1.y);
    }
    float ang = sign * (PI_F / 64.0f) * (float)l;
    float sn, cs;
    __sincosf(ang, &sn, &cs);
    float2 t = cmul(v1, cs, sn);
    float2 e = v0;
    v0 = make_float2(e.x + t.x, e.y + t.y);
    v1 = make_float2(e.x - t.x, e.y - t.y);
}

// ---- forward z FFT with tile merge fused in ----
__global__ __launch_bounds__(512) void fft_z_merge(const float* __restrict__ tiles,
                                                   float2* __restrict__ C) {
    int w = threadIdx.x >> 6, l = threadIdx.x & 63;
    int line = (blockIdx.x << 3) + w;
    int gx = line >> 7, gy = line & 127;
    int bx = gx >> 3, ox = gx & 7;
    int by = gy >> 3, oy = gy & 7;
    int nx = (ox >= 5) ? 2 : 1, ny = (oy >= 5) ? 2 : 1;
    int bxs[2] = {bx, (bx + 1) & 15}, lxs[2] = {ox + 3, ox - 5};
    int bys[2] = {by, (by + 1) & 15}, lys[2] = {oy + 3, oy - 5};
    float2 v0, v1;
#pragma unroll
    for (int h = 0; h < 2; h++) {
        int gz = l + (h << 6);
        int bz = gz >> 3, oz = gz & 7;
        int nz = (oz >= 5) ? 2 : 1;
        int bzs[2] = {bz, (bz + 1) & 15}, lzs[2] = {oz + 3, oz - 5};
        float v = 0.0f;
        for (int i = 0; i < nx; i++)
            for (int j = 0; j < ny; j++) {
                int bxy = (bxs[i] << 8) | (bys[j] << 4);
                int lo = lxs[i] * T2 + lys[j] * TILE_D;
                for (int k = 0; k < nz; k++)
                    v += tiles[(size_t)(bxy | bzs[k]) * TSTRIDE + lo + lzs[k]];
            }
        if (h == 0) v0 = make_float2(v, 0.0f);
        else v1 = make_float2(v, 0.0f);
    }
    wave_fft128_dif(v0, v1, l, -1.0f);
    int base = line << 7;
    C[base + l] = v0;
    C[base + l + 64] = v1;
}

// ---- inverse z FFT (DIT), writes real potential mesh as float ----
__global__ __launch_bounds__(512) void fft_z_phi(const float2* __restrict__ C,
                                                 float* __restrict__ phi) {
    int w = threadIdx.x >> 6, l = threadIdx.x & 63;
    int line = (blockIdx.x << 3) + w;
    int base = line << 7;
    float2 v0 = C[base + l];
    float2 v1 = C[base + l + 64];
    wave_fft128_dit(v0, v1, l, 1.0f);
    phi[base + l] = v0.x;
    phi[base + l + 64] = v1.x;
}

// ---- FFT along strided dim (y). DIF=1 fwd, DIF=0 inv. 16-z chunks, LDS transpose. ---
template <int DIF>
__global__ __launch_bounds__(512) void fft_t(float2* __restrict__ C, int LS, int OS,
                                             float sign) {
    __shared__ float2 lds[128 * ST];
    int tid = threadIdx.x;
    int p = blockIdx.x >> 3;
    int z0 = (blockIdx.x & 7) << 4;
    int base = p * OS + z0;
#pragma unroll
    for (int k = 0; k < 2; k++) {
        int e = tid + (k << 9);
        int ll = e >> 3, zq = e & 7;
        float4 f = ((const float4*)C)[(base >> 1) + ll * (LS >> 1) + zq];
        lds[ll * ST + 2 * zq] = make_float2(f.x, f.y);
        lds[ll * ST + 2 * zq + 1] = make_float2(f.z, f.w);
    }
    __syncthreads();
    int w = tid >> 6, l = tid & 63;
#pragma unroll
    for (int c = 0; c < 2; c++) {
        int zt = (w << 1) | c;
        float2 v0 = lds[l * ST + zt];
        float2 v1 = lds[(l + 64) * ST + zt];
        if (DIF) wave_fft128_dif(v0, v1, l, sign);
        else wave_fft128_dit(v0, v1, l, sign);
        lds[l * ST + zt] = v0;
        lds[(l + 64) * ST + zt] = v1;
    }
    __syncthreads();
#pragma unroll
    for (int k = 0; k < 2; k++) {
        int e = tid + (k << 9);
        int ll = e >> 3, zq = e & 7;
        float2 a = lds[ll * ST + 2 * zq];
        float2 b = lds[ll * ST + 2 * zq + 1];
        ((float4*)C)[(base >> 1) + ll * (LS >> 1) + zq] = make_float4(a.x, a.y, b.x, b.y);
    }
}

// ---------------- scrambled-order m and |b|^-2 tables ----------------
__device__ __forceinline__ float bmod2f(int x) {
    float th = (TWO_PI_F / (float)KDIM) * (float)x;
    float s1, c1, s2, c2;
    __sincosf(th, &s1, &c1);
    __sincosf(th + th, &s2, &c2);
    float dr = 0.16666667f + 0.66666667f * c1 + 0.16666667f * c2;
    float di = 0.66666667f * s1 + 0.16666667f * s2;
    float d2 = dr * dr + di * di;
    return 1.0f / fmaxf(d2, 1e-12f);
}

__global__ void tbl_kernel(float* __restrict__ mtblS, float* __restrict__ btblS) {
    int i = threadIdx.x;
    if (i < KDIM) {
        int r = brev7(i);
        mtblS[i] = (float)(r < 64 ? r : r - 128);
        btblS[i] = bmod2f(r);
    }
}

// --------- fused: fwd x-DIF + scale (scrambled order) + energy + inv x-DIT ---------
__global__ __launch_bounds__(512) void fft_x_scale(float2* __restrict__ C,
                                                   const float* __restrict__ cell,
                                                   const float* __restrict__ mtblS,
                                                   const float* __restrict__ btblS,
                                                   float* __restrict__ scale_part) {
    __shared__ float2 lds[128 * ST];
    __shared__ float red[8];
    const int LS = KDIM * KDIM, OS = KDIM;
    int tid = threadIdx.x;
    int p = blockIdx.x >> 3;            // y slot
    int z0 = (blockIdx.x & 7) << 4;     // z chunk
    int base = p * OS + z0;
#pragma unroll
    for (int k = 0; k < 2; k++) {
        int e = tid + (k << 9);
        int ll = e >> 3, zq = e & 7;
        float4 f = ((const float4*)C)[(base >> 1) + ll * (LS >> 1) + zq];
        lds[ll * ST + 2 * zq] = make_float2(f.x, f.y);
        lds[ll * ST + 2 * zq + 1] = make_float2(f.z, f.w);
    }
    __syncthreads();
    int w = tid >> 6, l = tid & 63;
    float inv[9], det;
    inv3x3(cell, inv, &det);
    float my = mtblS[p];
    float by = btblS[p];
    float contrib = 0.0f;
#pragma unroll
    for (int c = 0; c < 2; c++) {
        int zt = (w << 1) | c;
        float2 v0 = lds[l * ST + zt];
        float2 v1 = lds[(l + 64) * ST + zt];
        wave_fft128_dif(v0, v1, l, -1.0f);
        int z = z0 + zt;
        float mz = mtblS[z];
        float byz = by * btblS[z];
#pragma unroll
        for (int h = 0; h < 2; h++) {
            int xs = l + (h << 6);      // x slot
            float mx = mtblS[xs];
            float kx = TWO_PI_F * (mx * inv[0] + my * inv[1] + mz * inv[2]);
            float ky = TWO_PI_F * (mx * inv[3] + my * inv[4] + mz * inv[5]);
            float kz = TWO_PI_F * (mx * inv[6] + my * inv[7] + mz * inv[8]);
            float k2 = kx * kx + ky * ky + kz * kz;
            float A = 0.0f;
            if (k2 > 0.0f)
                A = __expf(-k2 / (4.0f * ALPHA_F * ALPHA_F)) / k2 * btblS[xs] * byz;
            float2& v = h ? v1 : v0;
            contrib += A * (v.x * v.x + v.y * v.y);
            v.x *= A;
            v.y *= A;
        }
        wave_fft128_dit(v0, v1, l, 1.0f);
        lds[l * ST + zt] = v0;
        lds[(l + 64) * ST + zt] = v1;
    }
#pragma unroll
    for (int off = 32; off; off >>= 1) contrib += __shfl_down(contrib, off);
    if (l == 0) red[w] = contrib;
    __syncthreads();
    if (tid == 0) {
        float v = 0.0f;
        for (int i = 0; i < 8; i++) v += red[i];
        scale_part[blockIdx.x] = v;
    }
#pragma unroll
    for (int k = 0; k < 2; k++) {
        int e = tid + (k << 9);
        int ll = e >> 3, zq = e & 7;
        float2 a = lds[ll * ST + 2 * zq];
        float2 b = lds[ll * ST + 2 * zq + 1];
        ((float4*)C)[(base >> 1) + ll * (LS >> 1) + zq] = make_float4(a.x, a.y, b.x, b.y);
    }
}

// ---------------- energy finalize ----------------
__global__ __launch_bounds__(256) void finalize_kernel(const float* __restrict__ scale_part,
                                                       const float* __restrict__ q2_part,
                                                       int nq2,
                                                       const float* __restrict__ cell,
                                                       float* __restrict__ out) {
    __shared__ double sd[256];
    int tid = threadIdx.x;
    double es = 0.0;
    for (int i = tid; i < NSCALE_BLK; i += 256) es += (double)scale_part[i];
    double q2 = 0.0;
    for (int i = tid; i < nq2; i += 256) q2 += (double)q2_part[i];
    sd[tid] = es;
    __syncthreads();
    for (int s = 128; s; s >>= 1) {
        if (tid < s) sd[tid] += sd[tid + s];
        __syncthreads();
    }
    double esum = sd[0];
    __syncthreads();
    sd[tid] = q2;
    __syncthreads();
    for (int s = 128; s; s >>= 1) {
        if (tid < s) sd[tid] += sd[tid + s];
        __syncthreads();
    }
    if (tid == 0) {
        float inv[9], det;
        inv3x3(cell, inv, &det);
        double c = (double)KE_F * 2.0 * 3.14159265358979323846 / (double)det;
        double e = c * esum -
                   (double)KE_F * (double)ALPHA_F / 1.7724538509055160273 * sd[0];
        out[0] = (float)e;
    }
}

// ------- force gather: atoms processed in bin-sorted order for mesh L2 locality ------
__global__ __launch_bounds__(256) void gather_kernel(const float* __restrict__ pos,
                                                     const float* __restrict__ chg,
                                                     const float* __restrict__ cell,
                                                     const int* __restrict__ binatoms,
                                                     const float* __restrict__ phi,
                                                     float* __restrict__ out, int n) {
    int a = blockIdx.x * blockDim.x + threadIdx.x;
    if (a >= n) return;
    int i = binatoms[a];
    float inv[9], det;
    inv3x3(cell, inv, &det);
    float wgt[3][4], dwg[3][4];
    int idx[3][4];
    atom_setup(pos, inv, i, wgt, dwg, idx);
    float acc0 = 0.0f, acc1 = 0.0f, acc2 = 0.0f;
#pragma unroll
    for (int j0 = 0; j0 < 4; j0++) {
        int r0 = idx[0][j0] << 14;
        float wx = wgt[0][j0], dx = dwg[0][j0];
#pragma unroll
        for (int j1 = 0; j1 < 4; j1++) {
            int r1 = r0 + (idx[1][j1] << 7);
            float wy = wgt[1][j1], dy = dwg[1][j1];
            float c00 = wx * wy;
            float c01 = wx * dy;
            float c02 = dx * wy;
#pragma unroll
            for (int j2 = 0; j2 < 4; j2++) {
                float p = phi[r1 + idx[2][j2]];
                float wz = wgt[2][j2], dz = dwg[2][j2];
                acc0 += p * c02 * wz;
                acc1 += p * c01 * wz;
                acc2 += p * c00 * dz;
            }
        }
    }
    float qi = chg[i];
    float c = KE_F * TWO_PI_F / det;
    float fac = -2.0f * c * qi * (float)KDIM;
    out[1 + 3 * i + 0] = fac * (acc0 * inv[0] + acc1 * inv[1] + acc2 * inv[2]);
    out[1 + 3 * i + 1] = fac * (acc0 * inv[3] + acc1 * inv[4] + acc2 * inv[5]);
    out[1 + 3 * i + 2] = fac * (acc0 * inv[6] + acc1 * inv[7] + acc2 * inv[8]);
}

extern "C" void kernel_launch(void* const* d_in, const int* in_sizes, int n_in,
                              void* d_out, int out_size, void* d_ws, size_t ws_size,
                              hipStream_t stream) {
    const float* pos = (const float*)d_in[0];
    const float* chg = (const float*)d_in[1];
    const float* cell = (const float*)d_in[2];
    float* out = (float*)d_out;
    int n = in_sizes[1];
    int nb = (n + 255) / 256;

    char* w = (char*)d_ws;
    float2* C = (float2*)w;                       // 16.78 MB; records alias this
    size_t off = (size_t)NTOT * sizeof(float2);
    float* tiles = (float*)(w + off);             // 22.02 MB; phi aliases this
    off += (size_t)NBINS * TSTRIDE * sizeof(float);
    int* counts = (int*)(w + off);                // NBINS
    off += NBINS * sizeof(int);
    int* cursor = (int*)(w + off);                // NBINS
    off += NBINS * sizeof(int);
    int* starts = (int*)(w + off);                // NBINS+1
    off += (NBINS + 1) * sizeof(int);
    int* binatoms = (int*)(w + off);              // n
    off += (size_t)n * sizeof(int);
    float* scale_part = (float*)(w + off);        // NSCALE_BLK
    off += NSCALE_BLK * sizeof(float);
    float* q2_part = (float*)(w + off);           // nb
    off += (size_t)nb * sizeof(float);
    float* mtblS = (float*)(w + off);             // 128
    off += KDIM * sizeof(float);
    float* btblS = (float*)(w + off);             // 128

    float* records = (float*)C;                   // dead after spread_bins
    float* phi = (float*)tiles;                   // tiles dead after fft_z_merge

    zero_kernel<<<(NBINS + 255) / 256, 256, 0, stream>>>(counts, cursor);
    tbl_kernel<<<1, 128, 0, stream>>>(mtblS, btblS);
    hist_kernel<<<nb, 256, 0, stream>>>(pos, chg, cell, counts, q2_part, n);
    scan_kernel<<<1, 256, 0, stream>>>(counts, starts);
    scatter_kernel<<<nb, 256, 0, stream>>>(pos, chg, cell, starts, cursor, records,
                                           binatoms, n);
    spread_bins_kernel<<<NBINS, 256, 0, stream>>>(records, starts, tiles);

    fft_z_merge<<<2048, 512, 0, stream>>>(tiles, C);                    // fwd z (DIF)
    fft_t<1><<<1024, 512, 0, stream>>>(C, KDIM, KDIM * KDIM, -1.0f);    // fwd y (DIF)
    fft_x_scale<<<NSCALE_BLK, 512, 0, stream>>>(C, cell, mtblS, btblS, scale_part);
    fft_t<0><<<1024, 512, 0, stream>>>(C, KDIM, KDIM * KDIM, 1.0f);     // inv y (DIT)
    fft_z_phi<<<2048, 512, 0, stream>>>(C, phi);                        // inv z (DIT)

    finalize_kernel<<<1, 256, 0, stream>>>(scale_part, q2_part, nb, cell, out);
    gather_kernel<<<nb, 256, 0, stream>>>(pos, chg, cell, binatoms, phi, out, n);
}